// Round 7
// baseline (1577.743 us; speedup 1.0000x reference)
//
#include <hip/hip_runtime.h>
#include <hip/hip_bf16.h>

#define NB 512
#define NL 160
#define ND 350

typedef float f32x4 __attribute__((ext_vector_type(4)));
typedef __bf16 bf16x8 __attribute__((ext_vector_type(8)));
typedef unsigned short u16x8 __attribute__((ext_vector_type(8)));

// ---------------- wave (64-lane) reductions ----------------
__device__ __forceinline__ float wsum(float v){
#pragma unroll
  for (int o = 32; o; o >>= 1) v += __shfl_xor(v, o, 64);
  return v;
}
__device__ __forceinline__ float wmaxf(float v){
#pragma unroll
  for (int o = 32; o; o >>= 1) v = fmaxf(v, __shfl_xor(v, o, 64));
  return v;
}
__device__ __forceinline__ unsigned long long wmax64(unsigned long long v){
#pragma unroll
  for (int o = 32; o; o >>= 1){
    unsigned long long u = __shfl_xor(v, o, 64);
    v = (u > v) ? u : v;
  }
  return v;
}

// float -> bf16 bits (RNE), and back
__device__ __forceinline__ unsigned short f2bf(float f){
  unsigned x = __float_as_uint(f);
  unsigned r = (x + 0x7fffu + ((x >> 16) & 1u)) >> 16;
  return (unsigned short)r;
}
__device__ __forceinline__ float bf2f(unsigned short u){
  return __uint_as_float(((unsigned)u) << 16);
}

// ---- embedding fetch helper ------------------------------------------------
__device__ __forceinline__ float emb_at(const float* __restrict__ wemb,
                                        const float* __restrict__ aemb,
                                        int attr_id, int tok_id, int d){
  return (d < 50) ? aemb[attr_id * 50 + d]
                  : wemb[(size_t)tok_id * 300 + (d - 50)];
}

// ---------------- 0. fp32 embedding plane: vec[bl][l][k], k in [0,352) ------
__global__ __launch_bounds__(256) void embed_f32(
    const int* __restrict__ tok, const int* __restrict__ attr,
    const float* __restrict__ wemb, const float* __restrict__ aemb,
    float* __restrict__ vec, int CB, int b0){
  int idx = blockIdx.x * 256 + threadIdx.x;
  if (idx >= CB * 160 * 352) return;
  int k = idx % 352;
  int row = idx / 352;          // bl*160 + l
  int l = row % 160;
  int b = b0 + row / 160;
  float v = 0.f;
  if (k < 50)       v = aemb[attr[l * NB + b] * 50 + k];
  else if (k < 350) v = wemb[(size_t)tok[l * NB + b] * 300 + (k - 50)];
  vec[idx] = v;
}

// ---------------- 1. att[b] = Lv_b @ Rv_b^T (fp32), masked; att and attT ----
// One block per batch. 256 threads as 16x16, 10x10 micro-tile (same layout
// and epilogue as the validated round-5 kernel). Staging now reads the
// precomputed fp32 vec planes with float4; inner loop does 4 k per LDS read.
__global__ __launch_bounds__(256, 2) void att_f32(
    const float* __restrict__ lv, const float* __restrict__ rv,
    const int* __restrict__ llen, const int* __restrict__ rlen,
    float* __restrict__ att, float* __restrict__ attT, int b0){
  __shared__ __align__(16) char smem[2 * 160 * 36 * 4];   // 46,080 B
  float (*Lt)[36] = (float (*)[36])smem;
  float (*Rt)[36] = (float (*)[36])(smem + 160 * 36 * 4);
  float (*Tb)[164] = (float (*)[164])smem;   // epilogue reuse (10.5 KB)

  int bl = blockIdx.x;
  int b  = b0 + bl;
  int tid = threadIdx.x;
  int tx = tid & 15, ty = tid >> 4;
  const float* __restrict__ Lp = lv + (size_t)bl * 160 * 352;
  const float* __restrict__ Rp = rv + (size_t)bl * 160 * 352;

  float acc[10][10];
#pragma unroll
  for (int i = 0; i < 10; ++i)
#pragma unroll
    for (int j = 0; j < 10; ++j) acc[i][j] = 0.f;

  for (int kc = 0; kc < 352; kc += 32){
    __syncthreads();
    // stage 160 rows x 32 k per side: 1280 float4 per side, 5 per thread
#pragma unroll
    for (int it = 0; it < 5; ++it){
      int i = tid + it * 256;
      int r = i >> 3, q = i & 7;
      size_t go = (size_t)r * 352 + kc + q * 4;
      *(f32x4*)&Lt[r][q * 4] = *(const f32x4*)(Lp + go);
      *(f32x4*)&Rt[r][q * 4] = *(const f32x4*)(Rp + go);
    }
    __syncthreads();
#pragma unroll 1
    for (int g = 0; g < 8; ++g){
      f32x4 Rb[10];
#pragma unroll
      for (int j = 0; j < 10; ++j) Rb[j] = *(const f32x4*)&Rt[tx + 16 * j][g * 4];
#pragma unroll
      for (int i = 0; i < 10; ++i){
        f32x4 La = *(const f32x4*)&Lt[ty + 16 * i][g * 4];
#pragma unroll
        for (int j = 0; j < 10; ++j){
          acc[i][j] = fmaf(La[0], Rb[j][0], acc[i][j]);
          acc[i][j] = fmaf(La[1], Rb[j][1], acc[i][j]);
          acc[i][j] = fmaf(La[2], Rb[j][2], acc[i][j]);
          acc[i][j] = fmaf(La[3], Rb[j][3], acc[i][j]);
        }
      }
    }
  }

  int ll = llen[b], rl = rlen[b];
#pragma unroll
  for (int i = 0; i < 10; ++i){
    bool lok = (ty + 16 * i) < ll;
#pragma unroll
    for (int j = 0; j < 10; ++j){
      if (!(lok && ((tx + 16 * j) < rl))) acc[i][j] = 0.f;
    }
  }
  // row-major store: att[bl][l][r]
#pragma unroll
  for (int i = 0; i < 10; ++i){
    size_t rowb = ((size_t)bl * 160 + ty + 16 * i) * 160;
#pragma unroll
    for (int j = 0; j < 10; ++j) att[rowb + tx + 16 * j] = acc[i][j];
  }
  // transposed store via LDS (verbatim from validated round-5 kernel)
  for (int jj = 0; jj < 10; ++jj){
    __syncthreads();
#pragma unroll
    for (int i = 0; i < 10; ++i) Tb[tx][ty + 16 * i] = acc[i][jj];
    __syncthreads();
    for (int i2 = tid; i2 < 16 * 160; i2 += 256){
      int rloc = i2 / 160, l = i2 - rloc * 160;
      attT[((size_t)bl * 160 + 16 * jj + rloc) * 160 + l] = Tb[rloc][l];
    }
  }
}

// ---------------- 2. per-row softmax+renorm, w, top-3, counter, |diff| ------
// attR rows contiguous over kv. Output split-bf16 planes, K-padded to 352.
// (validated round-5 version)
__global__ __launch_bounds__(256) void proc_kernel(
    const float* __restrict__ attR,
    const int* __restrict__ ownLen, const int* __restrict__ kvLen,
    const int* __restrict__ ownTok, const int* __restrict__ ownAttr,
    const int* __restrict__ kvTok,  const int* __restrict__ kvAttr,
    const float* __restrict__ wemb, const float* __restrict__ aemb,
    unsigned short* __restrict__ outH, unsigned short* __restrict__ outL,
    int CB, int b0){
  int lane = threadIdx.x & 63;
  int wid = blockIdx.x * 4 + (threadIdx.x >> 6);
  int q  = wid / CB;
  int bl = wid - q * CB;
  int b  = b0 + bl;
  int nOwn = ownLen[b], nKv = kvLen[b];
  const float* __restrict__ row = attR + ((size_t)bl * 160 + q) * 160;
  int rr0 = lane, rr1 = lane + 64, rr2 = lane + 128;
  bool has2 = rr2 < 160;
  float a0 = row[rr0];
  float a1 = row[rr1];
  float a2 = has2 ? row[rr2] : 0.f;
  float v0 = (rr0 < nKv) ? a0 : -10.f;
  float v1 = (rr1 < nKv) ? a1 : -10.f;
  float v2 = has2 ? ((rr2 < nKv) ? a2 : -10.f) : -1e30f;
  float m = wmaxf(fmaxf(v0, fmaxf(v1, v2)));
  float e0 = expf(v0 - m);
  float e1 = expf(v1 - m);
  float e2 = has2 ? expf(v2 - m) : 0.f;
  float ssum = wsum(e0 + e1 + e2);
  float p0 = (rr0 < nKv) ? e0 / ssum : 0.f;
  float p1 = (rr1 < nKv) ? e1 / ssum : 0.f;
  float p2 = (has2 && rr2 < nKv) ? e2 / ssum : 0.f;
  float s2 = wsum(p0 + p1 + p2);
  float inv = 1.f / (s2 + 1e-13f);
  p0 *= inv; p1 *= inv; p2 *= inv;
  float sp  = wsum(p0 + p1 + p2);
  float sp2 = wsum(p0 * p0 + p1 * p1 + p2 * p2);
  float kf = (float)nKv;
  float mean = sp / kf;
  float w = (sp2 / kf - mean * mean) / fmaxf(mean, 0.001f);
  // top-3, JAX tie-break (lower index wins ties)
  unsigned long long key0 = (((unsigned long long)__float_as_uint(p0)) << 32) | (unsigned)(0xFFFFFFFFu - rr0);
  unsigned long long key1 = (((unsigned long long)__float_as_uint(p1)) << 32) | (unsigned)(0xFFFFFFFFu - rr1);
  unsigned long long key2 = has2 ? ((((unsigned long long)__float_as_uint(p2)) << 32) | (unsigned)(0xFFFFFFFFu - rr2)) : 0ull;
  float tv[3]; int ti[3];
#pragma unroll
  for (int kk = 0; kk < 3; ++kk){
    unsigned long long loc = key0 > key1 ? key0 : key1;
    loc = key2 > loc ? key2 : loc;
    unsigned long long g = wmax64(loc);
    tv[kk] = __uint_as_float((unsigned)(g >> 32));
    ti[kk] = (int)(0xFFFFFFFFu - (unsigned)g);
    if (key0 == g) key0 = 0ull;
    if (key1 == g) key1 = 0ull;
    if (key2 == g) key2 = 0ull;
  }
  float tsum = tv[0] + tv[1] + tv[2];
  float ad = 1.f / fmaxf(tsum, 0.001f);
  float c0 = tv[0] * ad, c1 = tv[1] * ad, c2 = tv[2] * ad;
  size_t rb = ((size_t)q * CB + bl) * 352;
  unsigned short* __restrict__ oh = outH + rb;
  unsigned short* __restrict__ ol = outL + rb;
  if (q < nOwn){
    int oa = ownAttr[q * NB + b],    ot = ownTok[q * NB + b];
    int a0i = kvAttr[ti[0] * NB + b], t0 = kvTok[ti[0] * NB + b];
    int a1i = kvAttr[ti[1] * NB + b], t1 = kvTok[ti[1] * NB + b];
    int a2i = kvAttr[ti[2] * NB + b], t2 = kvTok[ti[2] * NB + b];
    for (int d = lane; d < 352; d += 64){
      unsigned short hb = 0, lb = 0;
      if (d < 350){
        float ov = emb_at(wemb, aemb, oa, ot, d);
        float k0 = emb_at(wemb, aemb, a0i, t0, d);
        float k1 = emb_at(wemb, aemb, a1i, t1, d);
        float k2 = emb_at(wemb, aemb, a2i, t2, d);
        float cc = c0 * k0 + c1 * k1 + c2 * k2;
        float val = w * fabsf(ov - cc);
        hb = f2bf(val);
        lb = f2bf(val - bf2f(hb));
      }
      oh[d] = hb; ol[d] = lb;
    }
  } else {
    for (int d = lane; d < 352; d += 64){ oh[d] = 0; ol[d] = 0; }
  }
}

// ---------------- 3. pack conv weights into split-bf16 Wcat (640 x 352) ----
__global__ __launch_bounds__(256) void wcat_kernel(
    const float* __restrict__ w1, const float* __restrict__ w2,
    const float* __restrict__ w3,
    unsigned short* __restrict__ wcatH, unsigned short* __restrict__ wcatL){
  int idx = blockIdx.x * 256 + threadIdx.x;
  if (idx >= 640 * 352) return;
  int c = idx / 352, d = idx - c * 352;
  float v = 0.f;
  if (c < 600 && d < 350){
    if (c < 100) v = w1[c * 350 + d];
    else if (c < 300){
      int cc = c - 100; int j = cc / 100; int o = cc - j * 100;
      v = w2[(o * 350 + d) * 2 + j];
    } else {
      int cc = c - 300; int j = cc / 100; int o = cc - j * 100;
      v = w3[(o * 350 + d) * 3 + j];
    }
  }
  unsigned short hb = f2bf(v);
  wcatH[idx] = hb;
  wcatL[idx] = f2bf(v - bf2f(hb));
}

// ---------------- 4. P = A(Mx352) @ B^T(352x600) via split-bf16 MFMA -------
__global__ __launch_bounds__(256) void gemm_mfma(
    const unsigned short* __restrict__ Agh, const unsigned short* __restrict__ Agl,
    const unsigned short* __restrict__ Bgh, const unsigned short* __restrict__ Bgl,
    float* __restrict__ P){
  __shared__ unsigned short Ah[128][40];
  __shared__ unsigned short Al[128][40];
  __shared__ unsigned short Bh[64][40];
  __shared__ unsigned short Bl[64][40];
  const int m0 = blockIdx.x * 128;
  const int n0 = blockIdx.y * 64;
  const int tid = threadIdx.x;
  const int lane = tid & 63;
  const int wid  = tid >> 6;
  const int wr = wid >> 1, wc = wid & 1;
  const int lrow = lane & 15, lkg = lane >> 4;

  const int srow = tid >> 2;
  const int sq   = tid & 3;
  const size_t Aoff0 = (size_t)(m0 + srow)      * 352 + sq * 8;
  const size_t Aoff1 = (size_t)(m0 + srow + 64) * 352 + sq * 8;
  const size_t Boff  = (size_t)(n0 + srow)      * 352 + sq * 8;

  f32x4 acc[4][2];
#pragma unroll
  for (int i = 0; i < 4; ++i)
#pragma unroll
    for (int j = 0; j < 2; ++j) acc[i][j] = (f32x4){0.f, 0.f, 0.f, 0.f};

  u16x8 rah0 = *(const u16x8*)(Agh + Aoff0);
  u16x8 rah1 = *(const u16x8*)(Agh + Aoff1);
  u16x8 ral0 = *(const u16x8*)(Agl + Aoff0);
  u16x8 ral1 = *(const u16x8*)(Agl + Aoff1);
  u16x8 rbh  = *(const u16x8*)(Bgh + Boff);
  u16x8 rbl  = *(const u16x8*)(Bgl + Boff);

  for (int ks = 0; ks < 11; ++ks){
    __syncthreads();
    *(u16x8*)&Ah[srow][sq * 8]      = rah0;
    *(u16x8*)&Ah[srow + 64][sq * 8] = rah1;
    *(u16x8*)&Al[srow][sq * 8]      = ral0;
    *(u16x8*)&Al[srow + 64][sq * 8] = ral1;
    *(u16x8*)&Bh[srow][sq * 8]      = rbh;
    *(u16x8*)&Bl[srow][sq * 8]      = rbl;
    if (ks < 10){
      int k1 = (ks + 1) * 32;
      rah0 = *(const u16x8*)(Agh + Aoff0 + k1);
      rah1 = *(const u16x8*)(Agh + Aoff1 + k1);
      ral0 = *(const u16x8*)(Agl + Aoff0 + k1);
      ral1 = *(const u16x8*)(Agl + Aoff1 + k1);
      rbh  = *(const u16x8*)(Bgh + Boff + k1);
      rbl  = *(const u16x8*)(Bgl + Boff + k1);
    }
    __syncthreads();

    bf16x8 fah[4], fal[4], fbh[2], fbl[2];
#pragma unroll
    for (int mi = 0; mi < 4; ++mi){
      int r = wr * 64 + mi * 16 + lrow;
      fah[mi] = *(const bf16x8*)&Ah[r][lkg * 8];
      fal[mi] = *(const bf16x8*)&Al[r][lkg * 8];
    }
#pragma unroll
    for (int nj = 0; nj < 2; ++nj){
      int r = wc * 32 + nj * 16 + lrow;
      fbh[nj] = *(const bf16x8*)&Bh[r][lkg * 8];
      fbl[nj] = *(const bf16x8*)&Bl[r][lkg * 8];
    }
#pragma unroll
    for (int mi = 0; mi < 4; ++mi)
#pragma unroll
      for (int nj = 0; nj < 2; ++nj){
        acc[mi][nj] = __builtin_amdgcn_mfma_f32_16x16x32_bf16(fah[mi], fbh[nj], acc[mi][nj], 0, 0, 0);
        acc[mi][nj] = __builtin_amdgcn_mfma_f32_16x16x32_bf16(fal[mi], fbh[nj], acc[mi][nj], 0, 0, 0);
        acc[mi][nj] = __builtin_amdgcn_mfma_f32_16x16x32_bf16(fah[mi], fbl[nj], acc[mi][nj], 0, 0, 0);
      }
  }

#pragma unroll
  for (int mi = 0; mi < 4; ++mi){
#pragma unroll
    for (int nj = 0; nj < 2; ++nj){
      int col = n0 + wc * 32 + nj * 16 + lrow;
      if (col < 600){
        size_t rowb = (size_t)(m0 + wr * 64 + mi * 16 + lkg * 4) * 600 + col;
#pragma unroll
        for (int r = 0; r < 4; ++r)
          P[rowb + (size_t)r * 600] = acc[mi][nj][r];
      }
    }
  }
}

// ---------------- 5. shift-combine + bias + relu + masked max over t --------
__global__ __launch_bounds__(320) void combine_kernel(
    const float* __restrict__ P, const int* __restrict__ len,
    const float* __restrict__ b1, const float* __restrict__ b2,
    const float* __restrict__ b3, float* __restrict__ feats,
    int sideoff, int CB, int b0){
  int bl = blockIdx.x;
  int b = b0 + bl;
  int c = threadIdx.x;
  if (c >= 300) return;
  int n = len[b];
  float vmax = -1e30f;
  if (c < 100){
    float bias = b1[c];
    for (int t = 0; t < n; ++t){
      float v = P[(size_t)(t * CB + bl) * 600 + c] + bias;
      vmax = fmaxf(vmax, fmaxf(v, 0.f));
    }
  } else if (c < 200){
    int o = c - 100;
    float bias = b2[o];
    for (int t = 0; t + 1 < n; ++t){
      float v = P[(size_t)(t * CB + bl) * 600 + 100 + o]
              + P[(size_t)((t + 1) * CB + bl) * 600 + 200 + o] + bias;
      vmax = fmaxf(vmax, fmaxf(v, 0.f));
    }
  } else {
    int o = c - 200;
    float bias = b3[o];
    for (int t = 0; t + 2 < n; ++t){
      float v = P[(size_t)(t * CB + bl) * 600 + 300 + o]
              + P[(size_t)((t + 1) * CB + bl) * 600 + 400 + o]
              + P[(size_t)((t + 2) * CB + bl) * 600 + 500 + o] + bias;
      vmax = fmaxf(vmax, fmaxf(v, 0.f));
    }
  }
  feats[(size_t)b * 600 + sideoff + c] = vmax;
}

// ---------------- 6. dense head ---------------------------------------------
__global__ __launch_bounds__(64) void dense_kernel(
    const float* __restrict__ feats,
    const float* __restrict__ w1, const float* __restrict__ b1,
    const float* __restrict__ w2, const float* __restrict__ b2,
    float* __restrict__ out){
  __shared__ float fs[600];
  __shared__ float hs[60];
  int b = blockIdx.x, tid = threadIdx.x;
  for (int i = tid; i < 600; i += 64) fs[i] = feats[(size_t)b * 600 + i];
  __syncthreads();
  if (tid < 60){
    float s = b1[tid];
    for (int d = 0; d < 600; ++d) s = fmaf(fs[d], w1[d * 60 + tid], s);
    hs[tid] = fmaxf(s, 0.f);
  }
  __syncthreads();
  if (tid < 2){
    float s = b2[tid];
    for (int j = 0; j < 60; ++j) s = fmaf(hs[j], w2[j * 2 + tid], s);
    out[b * 2 + tid] = s;
  }
}

// ---------------- launch ----------------------------------------------------
extern "C" void kernel_launch(void* const* d_in, const int* in_sizes, int n_in,
                              void* d_out, int out_size, void* d_ws, size_t ws_size,
                              hipStream_t stream){
  const int*   l_tok = (const int*)d_in[0];
  const int*   l_att = (const int*)d_in[1];
  const int*   l_len = (const int*)d_in[2];
  const int*   r_tok = (const int*)d_in[3];
  const int*   r_att = (const int*)d_in[4];
  const int*   r_len = (const int*)d_in[5];
  const float* wemb  = (const float*)d_in[6];
  const float* aemb  = (const float*)d_in[7];
  const float* cw1   = (const float*)d_in[8];
  const float* cb1   = (const float*)d_in[9];
  const float* cw2   = (const float*)d_in[10];
  const float* cb2   = (const float*)d_in[11];
  const float* cw3   = (const float*)d_in[12];
  const float* cb3   = (const float*)d_in[13];
  const float* dw1   = (const float*)d_in[14];
  const float* db1   = (const float*)d_in[15];
  const float* dw2   = (const float*)d_in[16];
  const float* db2   = (const float*)d_in[17];
  float* out = (float*)d_out;

  // per-batch bytes: att+attT 204800, lv/rv fp32 450560, lc/rc planes 450560,
  // P 384000 => 1,489,920.  persistent: feats 1,228,800 + wcat 901,120.
  // CB power of two (>=4) so 128 | 160*CB.
  int CB = 512;
  while (CB > 4){
    size_t need = (size_t)CB * 1489920 + 2129920 + 4096;
    if (need <= ws_size) break;
    CB >>= 1;
  }

  char* p = (char*)d_ws;
  float* feats = (float*)p;                   p += 1228800;
  unsigned short* wcatH = (unsigned short*)p; p += 450560;
  unsigned short* wcatL = (unsigned short*)p; p += 450560;
  float* att  = (float*)p;                    p += (size_t)CB * 102400;
  float* attT = (float*)p;                    p += (size_t)CB * 102400;
  float* lv   = (float*)p;                    p += (size_t)CB * 225280;
  float* rv   = (float*)p;                    p += (size_t)CB * 225280;
  unsigned short* lcH = (unsigned short*)p;   p += (size_t)CB * 112640;
  unsigned short* lcL = (unsigned short*)p;   p += (size_t)CB * 112640;
  unsigned short* rcH = (unsigned short*)p;   p += (size_t)CB * 112640;
  unsigned short* rcL = (unsigned short*)p;   p += (size_t)CB * 112640;
  float* P = (float*)p;

  wcat_kernel<<<880, 256, 0, stream>>>(cw1, cw2, cw3, wcatH, wcatL);

  int nch = NB / CB;
  dim3 gP(CB * 160 / 128, 10);
  for (int c = 0; c < nch; ++c){
    int b0 = c * CB;
    embed_f32<<<CB * 220, 256, 0, stream>>>(l_tok, l_att, wemb, aemb, lv, CB, b0);
    embed_f32<<<CB * 220, 256, 0, stream>>>(r_tok, r_att, wemb, aemb, rv, CB, b0);
    att_f32<<<CB, 256, 0, stream>>>(lv, rv, l_len, r_len, att, attT, b0);
    proc_kernel<<<CB * 40, 256, 0, stream>>>(att,  l_len, r_len,
                                             l_tok, l_att, r_tok, r_att,
                                             wemb, aemb, lcH, lcL, CB, b0);
    proc_kernel<<<CB * 40, 256, 0, stream>>>(attT, r_len, l_len,
                                             r_tok, r_att, l_tok, l_att,
                                             wemb, aemb, rcH, rcL, CB, b0);
    gemm_mfma<<<gP, 256, 0, stream>>>(lcH, lcL, wcatH, wcatL, P);
    combine_kernel<<<CB, 320, 0, stream>>>(P, l_len, cb1, cb2, cb3, feats, 0,   CB, b0);
    gemm_mfma<<<gP, 256, 0, stream>>>(rcH, rcL, wcatH, wcatL, P);
    combine_kernel<<<CB, 320, 0, stream>>>(P, r_len, cb1, cb2, cb3, feats, 300, CB, b0);
  }
  dense_kernel<<<NB, 64, 0, stream>>>(feats, dw1, db1, dw2, db2, out);
}

// Round 8
// 1202.208 us; speedup vs baseline: 1.3124x; 1.3124x over previous
//
#include <hip/hip_runtime.h>
#include <hip/hip_bf16.h>

#define NB 512
#define NL 160
#define ND 350

typedef float f32x4 __attribute__((ext_vector_type(4)));
typedef __bf16 bf16x8 __attribute__((ext_vector_type(8)));
typedef unsigned short u16x8 __attribute__((ext_vector_type(8)));

// ---------------- wave (64-lane) reductions ----------------
__device__ __forceinline__ float wsum(float v){
#pragma unroll
  for (int o = 32; o; o >>= 1) v += __shfl_xor(v, o, 64);
  return v;
}
__device__ __forceinline__ float wmaxf(float v){
#pragma unroll
  for (int o = 32; o; o >>= 1) v = fmaxf(v, __shfl_xor(v, o, 64));
  return v;
}
__device__ __forceinline__ unsigned long long wmax64(unsigned long long v){
#pragma unroll
  for (int o = 32; o; o >>= 1){
    unsigned long long u = __shfl_xor(v, o, 64);
    v = (u > v) ? u : v;
  }
  return v;
}

// float -> bf16 bits (RNE), and back
__device__ __forceinline__ unsigned short f2bf(float f){
  unsigned x = __float_as_uint(f);
  unsigned r = (x + 0x7fffu + ((x >> 16) & 1u)) >> 16;
  return (unsigned short)r;
}
__device__ __forceinline__ float bf2f(unsigned short u){
  return __uint_as_float(((unsigned)u) << 16);
}

// ---- embedding fetch helper ------------------------------------------------
__device__ __forceinline__ float emb_at(const float* __restrict__ wemb,
                                        const float* __restrict__ aemb,
                                        int attr_id, int tok_id, int d){
  return (d < 50) ? aemb[attr_id * 50 + d]
                  : wemb[(size_t)tok_id * 300 + (d - 50)];
}

// ---------------- 1. att[b] = Lv_b @ Rv_b^T (fp32), masked; att and attT ----
// One block per batch. Stages embeddings DIRECTLY from tables into LDS as
// float2 pairs (region-pure: 50/350 even; attr rows 200B and word rows 1200B
// are both 8B-aligned). Compute + epilogue identical to validated att_f32.
__global__ __launch_bounds__(256, 2) void att_direct(
    const int* __restrict__ l_tok, const int* __restrict__ l_att,
    const int* __restrict__ r_tok, const int* __restrict__ r_att,
    const float* __restrict__ wemb, const float* __restrict__ aemb,
    const int* __restrict__ llen, const int* __restrict__ rlen,
    float* __restrict__ att, float* __restrict__ attT, int b0){
  __shared__ __align__(16) char smem[2 * 160 * 36 * 4];   // 46,080 B
  float (*Lt)[36] = (float (*)[36])smem;
  float (*Rt)[36] = (float (*)[36])(smem + 160 * 36 * 4);
  float (*Tb)[164] = (float (*)[164])smem;   // epilogue alias (10.5 KB)
  __shared__ int ltk[160], lat[160], rtk[160], rat[160];

  int bl = blockIdx.x;
  int b  = b0 + bl;
  int tid = threadIdx.x;
  int tx = tid & 15, ty = tid >> 4;

  for (int i = tid; i < 160; i += 256){
    ltk[i] = l_tok[i * NB + b];
    lat[i] = l_att[i * NB + b];
    rtk[i] = r_tok[i * NB + b];
    rat[i] = r_att[i * NB + b];
  }

  float acc[10][10];
#pragma unroll
  for (int i = 0; i < 10; ++i)
#pragma unroll
    for (int j = 0; j < 10; ++j) acc[i][j] = 0.f;

  for (int kc = 0; kc < 352; kc += 32){
    __syncthreads();
    // stage 2 sides x 160 rows x 16 float2-pairs (32 k) = 5120 ops / 256 thr
#pragma unroll
    for (int it = 0; it < 20; ++it){
      int i = tid + it * 256;
      int side = i >= 2560;
      int rem = i - side * 2560;
      int r = rem >> 4, pr = rem & 15;
      int k0 = kc + pr * 2;
      float vx = 0.f, vy = 0.f;
      if (k0 < 50){
        int aid = side ? rat[r] : lat[r];
        const float* s = aemb + aid * 50 + k0;
        vx = s[0]; vy = s[1];
      } else if (k0 < 350){
        int tkn = side ? rtk[r] : ltk[r];
        const float* s = wemb + (size_t)tkn * 300 + (k0 - 50);
        vx = s[0]; vy = s[1];
      }
      float* dst = side ? &Rt[r][pr * 2] : &Lt[r][pr * 2];
      dst[0] = vx; dst[1] = vy;
    }
    __syncthreads();
#pragma unroll 1
    for (int g = 0; g < 8; ++g){
      f32x4 Rb[10];
#pragma unroll
      for (int j = 0; j < 10; ++j) Rb[j] = *(const f32x4*)&Rt[tx + 16 * j][g * 4];
#pragma unroll
      for (int i = 0; i < 10; ++i){
        f32x4 La = *(const f32x4*)&Lt[ty + 16 * i][g * 4];
#pragma unroll
        for (int j = 0; j < 10; ++j){
          acc[i][j] = fmaf(La[0], Rb[j][0], acc[i][j]);
          acc[i][j] = fmaf(La[1], Rb[j][1], acc[i][j]);
          acc[i][j] = fmaf(La[2], Rb[j][2], acc[i][j]);
          acc[i][j] = fmaf(La[3], Rb[j][3], acc[i][j]);
        }
      }
    }
  }

  int ll = llen[b], rl = rlen[b];
#pragma unroll
  for (int i = 0; i < 10; ++i){
    bool lok = (ty + 16 * i) < ll;
#pragma unroll
    for (int j = 0; j < 10; ++j){
      if (!(lok && ((tx + 16 * j) < rl))) acc[i][j] = 0.f;
    }
  }
  // row-major store: att[bl][l][r]
#pragma unroll
  for (int i = 0; i < 10; ++i){
    size_t rowb = ((size_t)bl * 160 + ty + 16 * i) * 160;
#pragma unroll
    for (int j = 0; j < 10; ++j) att[rowb + tx + 16 * j] = acc[i][j];
  }
  // transposed store via LDS (validated epilogue)
  for (int jj = 0; jj < 10; ++jj){
    __syncthreads();
#pragma unroll
    for (int i = 0; i < 10; ++i) Tb[tx][ty + 16 * i] = acc[i][jj];
    __syncthreads();
    for (int i2 = tid; i2 < 16 * 160; i2 += 256){
      int rloc = i2 / 160, l = i2 - rloc * 160;
      attT[((size_t)bl * 160 + 16 * jj + rloc) * 160 + l] = Tb[rloc][l];
    }
  }
}

// ---------------- 2. per-row softmax+renorm, w, top-3, counter, |diff| ------
// attR rows contiguous over kv. Output split-bf16 planes, K-padded to 352.
// Vectorized gather (f32x4 word region) + packed u32 stores; math identical.
__global__ __launch_bounds__(256) void proc_kernel(
    const float* __restrict__ attR,
    const int* __restrict__ ownLen, const int* __restrict__ kvLen,
    const int* __restrict__ ownTok, const int* __restrict__ ownAttr,
    const int* __restrict__ kvTok,  const int* __restrict__ kvAttr,
    const float* __restrict__ wemb, const float* __restrict__ aemb,
    unsigned short* __restrict__ outH, unsigned short* __restrict__ outL,
    int CB, int b0){
  int lane = threadIdx.x & 63;
  int wid = blockIdx.x * 4 + (threadIdx.x >> 6);
  int q  = wid / CB;
  int bl = wid - q * CB;
  int b  = b0 + bl;
  int nOwn = ownLen[b], nKv = kvLen[b];
  const float* __restrict__ row = attR + ((size_t)bl * 160 + q) * 160;
  int rr0 = lane, rr1 = lane + 64, rr2 = lane + 128;
  bool has2 = rr2 < 160;
  float a0 = row[rr0];
  float a1 = row[rr1];
  float a2 = has2 ? row[rr2] : 0.f;
  float v0 = (rr0 < nKv) ? a0 : -10.f;
  float v1 = (rr1 < nKv) ? a1 : -10.f;
  float v2 = has2 ? ((rr2 < nKv) ? a2 : -10.f) : -1e30f;
  float m = wmaxf(fmaxf(v0, fmaxf(v1, v2)));
  float e0 = expf(v0 - m);
  float e1 = expf(v1 - m);
  float e2 = has2 ? expf(v2 - m) : 0.f;
  float ssum = wsum(e0 + e1 + e2);
  float p0 = (rr0 < nKv) ? e0 / ssum : 0.f;
  float p1 = (rr1 < nKv) ? e1 / ssum : 0.f;
  float p2 = (has2 && rr2 < nKv) ? e2 / ssum : 0.f;
  float s2 = wsum(p0 + p1 + p2);
  float inv = 1.f / (s2 + 1e-13f);
  p0 *= inv; p1 *= inv; p2 *= inv;
  float sp  = wsum(p0 + p1 + p2);
  float sp2 = wsum(p0 * p0 + p1 * p1 + p2 * p2);
  float kf = (float)nKv;
  float mean = sp / kf;
  float w = (sp2 / kf - mean * mean) / fmaxf(mean, 0.001f);
  // top-3, JAX tie-break (lower index wins ties)
  unsigned long long key0 = (((unsigned long long)__float_as_uint(p0)) << 32) | (unsigned)(0xFFFFFFFFu - rr0);
  unsigned long long key1 = (((unsigned long long)__float_as_uint(p1)) << 32) | (unsigned)(0xFFFFFFFFu - rr1);
  unsigned long long key2 = has2 ? ((((unsigned long long)__float_as_uint(p2)) << 32) | (unsigned)(0xFFFFFFFFu - rr2)) : 0ull;
  float tv[3]; int ti[3];
#pragma unroll
  for (int kk = 0; kk < 3; ++kk){
    unsigned long long loc = key0 > key1 ? key0 : key1;
    loc = key2 > loc ? key2 : loc;
    unsigned long long g = wmax64(loc);
    tv[kk] = __uint_as_float((unsigned)(g >> 32));
    ti[kk] = (int)(0xFFFFFFFFu - (unsigned)g);
    if (key0 == g) key0 = 0ull;
    if (key1 == g) key1 = 0ull;
    if (key2 == g) key2 = 0ull;
  }
  float tsum = tv[0] + tv[1] + tv[2];
  float ad = 1.f / fmaxf(tsum, 0.001f);
  float c0 = tv[0] * ad, c1 = tv[1] * ad, c2 = tv[2] * ad;
  size_t rb = ((size_t)q * CB + bl) * 352;
  unsigned short* __restrict__ oh = outH + rb;
  unsigned short* __restrict__ ol = outL + rb;
  if (q < nOwn){
    int oa = ownAttr[q * NB + b],    ot = ownTok[q * NB + b];
    int a0i = kvAttr[ti[0] * NB + b], t0 = kvTok[ti[0] * NB + b];
    int a1i = kvAttr[ti[1] * NB + b], t1 = kvTok[ti[1] * NB + b];
    int a2i = kvAttr[ti[2] * NB + b], t2 = kvTok[ti[2] * NB + b];
    // attr region d in [0,50): scalar
    if (lane < 50){
      int d = lane;
      float ov = aemb[oa * 50 + d];
      float cc = c0 * aemb[a0i * 50 + d] + c1 * aemb[a1i * 50 + d]
               + c2 * aemb[a2i * 50 + d];
      float val = w * fabsf(ov - cc);
      unsigned short hb = f2bf(val);
      oh[d] = hb; ol[d] = f2bf(val - bf2f(hb));
    }
    // word region: 75 groups of float4 (wemb rows are 1200B = 16B-aligned)
    for (int j = lane; j < 75; j += 64){
      int d = 50 + j * 4;
      f32x4 ov = *(const f32x4*)(wemb + (size_t)ot * 300 + j * 4);
      f32x4 k0 = *(const f32x4*)(wemb + (size_t)t0 * 300 + j * 4);
      f32x4 k1 = *(const f32x4*)(wemb + (size_t)t1 * 300 + j * 4);
      f32x4 k2 = *(const f32x4*)(wemb + (size_t)t2 * 300 + j * 4);
      unsigned short hs[4], ls[4];
#pragma unroll
      for (int t = 0; t < 4; ++t){
        float cc = c0 * k0[t] + c1 * k1[t] + c2 * k2[t];
        float val = w * fabsf(ov[t] - cc);
        hs[t] = f2bf(val);
        ls[t] = f2bf(val - bf2f(hs[t]));
      }
      *(unsigned*)(oh + d)     = (unsigned)hs[0] | ((unsigned)hs[1] << 16);
      *(unsigned*)(oh + d + 2) = (unsigned)hs[2] | ((unsigned)hs[3] << 16);
      *(unsigned*)(ol + d)     = (unsigned)ls[0] | ((unsigned)ls[1] << 16);
      *(unsigned*)(ol + d + 2) = (unsigned)ls[2] | ((unsigned)ls[3] << 16);
    }
    if (lane == 0){
      *(unsigned*)(oh + 350) = 0u;
      *(unsigned*)(ol + 350) = 0u;
    }
  } else {
    for (int i = lane; i < 176; i += 64){
      *(unsigned*)(oh + i * 2) = 0u;
      *(unsigned*)(ol + i * 2) = 0u;
    }
  }
}

// ---------------- 3. pack conv weights into split-bf16 Wcat (640 x 352) ----
__global__ __launch_bounds__(256) void wcat_kernel(
    const float* __restrict__ w1, const float* __restrict__ w2,
    const float* __restrict__ w3,
    unsigned short* __restrict__ wcatH, unsigned short* __restrict__ wcatL){
  int idx = blockIdx.x * 256 + threadIdx.x;
  if (idx >= 640 * 352) return;
  int c = idx / 352, d = idx - c * 352;
  float v = 0.f;
  if (c < 600 && d < 350){
    if (c < 100) v = w1[c * 350 + d];
    else if (c < 300){
      int cc = c - 100; int j = cc / 100; int o = cc - j * 100;
      v = w2[(o * 350 + d) * 2 + j];
    } else {
      int cc = c - 300; int j = cc / 100; int o = cc - j * 100;
      v = w3[(o * 350 + d) * 3 + j];
    }
  }
  unsigned short hb = f2bf(v);
  wcatH[idx] = hb;
  wcatL[idx] = f2bf(v - bf2f(hb));
}

// ---------------- 3b. zero feats (atomicMax target) -------------------------
__global__ __launch_bounds__(256) void zero_feats(float* __restrict__ feats){
  int i = blockIdx.x * 256 + threadIdx.x;
  if (i < NB * 600) feats[i] = 0.f;
}

// ---------------- 4. P = A(Mx352) @ B^T(352x600) via split-bf16 MFMA -------
__global__ __launch_bounds__(256) void gemm_mfma(
    const unsigned short* __restrict__ Agh, const unsigned short* __restrict__ Agl,
    const unsigned short* __restrict__ Bgh, const unsigned short* __restrict__ Bgl,
    float* __restrict__ P){
  __shared__ unsigned short Ah[128][40];
  __shared__ unsigned short Al[128][40];
  __shared__ unsigned short Bh[64][40];
  __shared__ unsigned short Bl[64][40];
  const int m0 = blockIdx.x * 128;
  const int n0 = blockIdx.y * 64;
  const int tid = threadIdx.x;
  const int lane = tid & 63;
  const int wid  = tid >> 6;
  const int wr = wid >> 1, wc = wid & 1;
  const int lrow = lane & 15, lkg = lane >> 4;

  const int srow = tid >> 2;
  const int sq   = tid & 3;
  const size_t Aoff0 = (size_t)(m0 + srow)      * 352 + sq * 8;
  const size_t Aoff1 = (size_t)(m0 + srow + 64) * 352 + sq * 8;
  const size_t Boff  = (size_t)(n0 + srow)      * 352 + sq * 8;

  f32x4 acc[4][2];
#pragma unroll
  for (int i = 0; i < 4; ++i)
#pragma unroll
    for (int j = 0; j < 2; ++j) acc[i][j] = (f32x4){0.f, 0.f, 0.f, 0.f};

  u16x8 rah0 = *(const u16x8*)(Agh + Aoff0);
  u16x8 rah1 = *(const u16x8*)(Agh + Aoff1);
  u16x8 ral0 = *(const u16x8*)(Agl + Aoff0);
  u16x8 ral1 = *(const u16x8*)(Agl + Aoff1);
  u16x8 rbh  = *(const u16x8*)(Bgh + Boff);
  u16x8 rbl  = *(const u16x8*)(Bgl + Boff);

  for (int ks = 0; ks < 11; ++ks){
    __syncthreads();
    *(u16x8*)&Ah[srow][sq * 8]      = rah0;
    *(u16x8*)&Ah[srow + 64][sq * 8] = rah1;
    *(u16x8*)&Al[srow][sq * 8]      = ral0;
    *(u16x8*)&Al[srow + 64][sq * 8] = ral1;
    *(u16x8*)&Bh[srow][sq * 8]      = rbh;
    *(u16x8*)&Bl[srow][sq * 8]      = rbl;
    if (ks < 10){
      int k1 = (ks + 1) * 32;
      rah0 = *(const u16x8*)(Agh + Aoff0 + k1);
      rah1 = *(const u16x8*)(Agh + Aoff1 + k1);
      ral0 = *(const u16x8*)(Agl + Aoff0 + k1);
      ral1 = *(const u16x8*)(Agl + Aoff1 + k1);
      rbh  = *(const u16x8*)(Bgh + Boff + k1);
      rbl  = *(const u16x8*)(Bgl + Boff + k1);
    }
    __syncthreads();

    bf16x8 fah[4], fal[4], fbh[2], fbl[2];
#pragma unroll
    for (int mi = 0; mi < 4; ++mi){
      int r = wr * 64 + mi * 16 + lrow;
      fah[mi] = *(const bf16x8*)&Ah[r][lkg * 8];
      fal[mi] = *(const bf16x8*)&Al[r][lkg * 8];
    }
#pragma unroll
    for (int nj = 0; nj < 2; ++nj){
      int r = wc * 32 + nj * 16 + lrow;
      fbh[nj] = *(const bf16x8*)&Bh[r][lkg * 8];
      fbl[nj] = *(const bf16x8*)&Bl[r][lkg * 8];
    }
#pragma unroll
    for (int mi = 0; mi < 4; ++mi)
#pragma unroll
      for (int nj = 0; nj < 2; ++nj){
        acc[mi][nj] = __builtin_amdgcn_mfma_f32_16x16x32_bf16(fah[mi], fbh[nj], acc[mi][nj], 0, 0, 0);
        acc[mi][nj] = __builtin_amdgcn_mfma_f32_16x16x32_bf16(fal[mi], fbh[nj], acc[mi][nj], 0, 0, 0);
        acc[mi][nj] = __builtin_amdgcn_mfma_f32_16x16x32_bf16(fah[mi], fbl[nj], acc[mi][nj], 0, 0, 0);
      }
  }

#pragma unroll
  for (int mi = 0; mi < 4; ++mi){
#pragma unroll
    for (int nj = 0; nj < 2; ++nj){
      int col = n0 + wc * 32 + nj * 16 + lrow;
      if (col < 600){
        size_t rowb = (size_t)(m0 + wr * 64 + mi * 16 + lkg * 4) * 600 + col;
#pragma unroll
        for (int r = 0; r < 4; ++r)
          P[rowb + (size_t)r * 600] = acc[mi][nj][r];
      }
    }
  }
}

// ---------------- 5. combine: parallel over t-chunks, atomicMax into feats --
// grid (CB, 5): block (bl, tc) covers t in [tc*32, tc*32+32). All relu'd
// values are >= 0 so int-compare atomicMax on float bits is exact; feats
// pre-zeroed (true max >= 0 always since lengths >= 8).
__global__ __launch_bounds__(320) void combine_kernel(
    const float* __restrict__ P, const int* __restrict__ len,
    const float* __restrict__ b1, const float* __restrict__ b2,
    const float* __restrict__ b3, float* __restrict__ feats,
    int sideoff, int CB, int b0){
  int bl = blockIdx.x;
  int tc = blockIdx.y;
  int b = b0 + bl;
  int c = threadIdx.x;
  if (c >= 300) return;
  int n = len[b];
  int t0 = tc * 32;
  float vmax = 0.f;   // relu floor
  if (c < 100){
    int te = min(t0 + 32, n);
    float bias = b1[c];
    for (int t = t0; t < te; ++t)
      vmax = fmaxf(vmax, P[(size_t)(t * CB + bl) * 600 + c] + bias);
  } else if (c < 200){
    int o = c - 100;
    int te = min(t0 + 32, n - 1);
    float bias = b2[o];
    for (int t = t0; t < te; ++t)
      vmax = fmaxf(vmax, P[(size_t)(t * CB + bl) * 600 + 100 + o]
                       + P[(size_t)((t + 1) * CB + bl) * 600 + 200 + o] + bias);
  } else {
    int o = c - 200;
    int te = min(t0 + 32, n - 2);
    float bias = b3[o];
    for (int t = t0; t < te; ++t)
      vmax = fmaxf(vmax, P[(size_t)(t * CB + bl) * 600 + 300 + o]
                       + P[(size_t)((t + 1) * CB + bl) * 600 + 400 + o]
                       + P[(size_t)((t + 2) * CB + bl) * 600 + 500 + o] + bias);
  }
  atomicMax((int*)&feats[(size_t)b * 600 + sideoff + c], __float_as_int(vmax));
}

// ---------------- 6. dense head ---------------------------------------------
__global__ __launch_bounds__(64) void dense_kernel(
    const float* __restrict__ feats,
    const float* __restrict__ w1, const float* __restrict__ b1,
    const float* __restrict__ w2, const float* __restrict__ b2,
    float* __restrict__ out){
  __shared__ float fs[600];
  __shared__ float hs[60];
  int b = blockIdx.x, tid = threadIdx.x;
  for (int i = tid; i < 600; i += 64) fs[i] = feats[(size_t)b * 600 + i];
  __syncthreads();
  if (tid < 60){
    float s = b1[tid];
    for (int d = 0; d < 600; ++d) s = fmaf(fs[d], w1[d * 60 + tid], s);
    hs[tid] = fmaxf(s, 0.f);
  }
  __syncthreads();
  if (tid < 2){
    float s = b2[tid];
    for (int j = 0; j < 60; ++j) s = fmaf(hs[j], w2[j * 2 + tid], s);
    out[b * 2 + tid] = s;
  }
}

// ---------------- launch ----------------------------------------------------
extern "C" void kernel_launch(void* const* d_in, const int* in_sizes, int n_in,
                              void* d_out, int out_size, void* d_ws, size_t ws_size,
                              hipStream_t stream){
  const int*   l_tok = (const int*)d_in[0];
  const int*   l_att = (const int*)d_in[1];
  const int*   l_len = (const int*)d_in[2];
  const int*   r_tok = (const int*)d_in[3];
  const int*   r_att = (const int*)d_in[4];
  const int*   r_len = (const int*)d_in[5];
  const float* wemb  = (const float*)d_in[6];
  const float* aemb  = (const float*)d_in[7];
  const float* cw1   = (const float*)d_in[8];
  const float* cb1   = (const float*)d_in[9];
  const float* cw2   = (const float*)d_in[10];
  const float* cb2   = (const float*)d_in[11];
  const float* cw3   = (const float*)d_in[12];
  const float* cb3   = (const float*)d_in[13];
  const float* dw1   = (const float*)d_in[14];
  const float* db1   = (const float*)d_in[15];
  const float* dw2   = (const float*)d_in[16];
  const float* db2   = (const float*)d_in[17];
  float* out = (float*)d_out;

  // per-batch bytes: att+attT 204800, lc/rc planes 450560, P 384000
  //   => 1,039,360.  persistent: feats 1,228,800 + wcat 901,120.
  // CB power of two (>=4) so 128 | 160*CB.
  int CB = 512;
  while (CB > 4){
    size_t need = (size_t)CB * 1039360 + 2129920 + 4096;
    if (need <= ws_size) break;
    CB >>= 1;
  }

  char* p = (char*)d_ws;
  float* feats = (float*)p;                   p += 1228800;
  unsigned short* wcatH = (unsigned short*)p; p += 450560;
  unsigned short* wcatL = (unsigned short*)p; p += 450560;
  float* att  = (float*)p;                    p += (size_t)CB * 102400;
  float* attT = (float*)p;                    p += (size_t)CB * 102400;
  unsigned short* lcH = (unsigned short*)p;   p += (size_t)CB * 112640;
  unsigned short* lcL = (unsigned short*)p;   p += (size_t)CB * 112640;
  unsigned short* rcH = (unsigned short*)p;   p += (size_t)CB * 112640;
  unsigned short* rcL = (unsigned short*)p;   p += (size_t)CB * 112640;
  float* P = (float*)p;

  wcat_kernel<<<880, 256, 0, stream>>>(cw1, cw2, cw3, wcatH, wcatL);
  zero_feats<<<1200, 256, 0, stream>>>(feats);

  int nch = NB / CB;
  dim3 gP(CB * 160 / 128, 10);
  dim3 gC(CB, 5);
  for (int c = 0; c < nch; ++c){
    int b0 = c * CB;
    att_direct<<<CB, 256, 0, stream>>>(l_tok, l_att, r_tok, r_att, wemb, aemb,
                                       l_len, r_len, att, attT, b0);
    proc_kernel<<<CB * 40, 256, 0, stream>>>(att,  l_len, r_len,
                                             l_tok, l_att, r_tok, r_att,
                                             wemb, aemb, lcH, lcL, CB, b0);
    proc_kernel<<<CB * 40, 256, 0, stream>>>(attT, r_len, l_len,
                                             r_tok, r_att, l_tok, l_att,
                                             wemb, aemb, rcH, rcL, CB, b0);
    gemm_mfma<<<gP, 256, 0, stream>>>(lcH, lcL, wcatH, wcatL, P);
    combine_kernel<<<gC, 320, 0, stream>>>(P, l_len, cb1, cb2, cb3, feats, 0,   CB, b0);
    gemm_mfma<<<gP, 256, 0, stream>>>(rcH, rcL, wcatH, wcatL, P);
    combine_kernel<<<gC, 320, 0, stream>>>(P, r_len, cb1, cb2, cb3, feats, 300, CB, b0);
  }
  dense_kernel<<<NB, 64, 0, stream>>>(feats, dw1, db1, dw2, db2, out);
}

// Round 9
// 917.755 us; speedup vs baseline: 1.7191x; 1.3099x over previous
//
#include <hip/hip_runtime.h>
#include <hip/hip_bf16.h>

#define NB 512
#define NL 160
#define ND 350

typedef float f32x4 __attribute__((ext_vector_type(4)));
typedef __bf16 bf16x8 __attribute__((ext_vector_type(8)));
typedef unsigned short u16x8 __attribute__((ext_vector_type(8)));

// ---------------- wave (64-lane) reductions ----------------
__device__ __forceinline__ float wsum(float v){
#pragma unroll
  for (int o = 32; o; o >>= 1) v += __shfl_xor(v, o, 64);
  return v;
}
__device__ __forceinline__ float wmaxf(float v){
#pragma unroll
  for (int o = 32; o; o >>= 1) v = fmaxf(v, __shfl_xor(v, o, 64));
  return v;
}
__device__ __forceinline__ unsigned long long wmax64(unsigned long long v){
#pragma unroll
  for (int o = 32; o; o >>= 1){
    unsigned long long u = __shfl_xor(v, o, 64);
    v = (u > v) ? u : v;
  }
  return v;
}

// float -> bf16 bits (RNE), and back
__device__ __forceinline__ unsigned short f2bf(float f){
  unsigned x = __float_as_uint(f);
  unsigned r = (x + 0x7fffu + ((x >> 16) & 1u)) >> 16;
  return (unsigned short)r;
}
__device__ __forceinline__ float bf2f(unsigned short u){
  return __uint_as_float(((unsigned)u) << 16);
}

// ---- embedding fetch helper ------------------------------------------------
__device__ __forceinline__ float emb_at(const float* __restrict__ wemb,
                                        const float* __restrict__ aemb,
                                        int attr_id, int tok_id, int d){
  return (d < 50) ? aemb[attr_id * 50 + d]
                  : wemb[(size_t)tok_id * 300 + (d - 50)];
}

// ---------------- 1. att quadrants: 80x80 per block, grid (CB, 4) -----------
// blockIdx.y = quadrant (hl = y>>1 L-half, hr = y&1 R-half). Stages 80 L rows
// + 80 R rows of embeddings per K-chunk direct from tables (float2, region-
// pure). Thread tile 5x5; epilogue = validated transpose pattern, half-range.
__global__ __launch_bounds__(256, 2) void att_tile(
    const int* __restrict__ l_tok, const int* __restrict__ l_att,
    const int* __restrict__ r_tok, const int* __restrict__ r_att,
    const float* __restrict__ wemb, const float* __restrict__ aemb,
    const int* __restrict__ llen, const int* __restrict__ rlen,
    float* __restrict__ att, float* __restrict__ attT, int b0){
  __shared__ __align__(16) char smem[2 * 80 * 36 * 4];    // 23,040 B
  float (*Lt)[36] = (float (*)[36])smem;
  float (*Rt)[36] = (float (*)[36])(smem + 80 * 36 * 4);
  float (*Tb)[84] = (float (*)[84])smem;                  // epilogue alias
  __shared__ int tokA[80], attA[80], tokB[80], attB[80];

  const int bl = blockIdx.x;
  const int b  = b0 + bl;
  const int hl = blockIdx.y >> 1, hr = blockIdx.y & 1;
  const int tid = threadIdx.x;
  const int tx = tid & 15, ty = tid >> 4;

  if (tid < 80){
    tokA[tid] = l_tok[(hl * 80 + tid) * NB + b];
    attA[tid] = l_att[(hl * 80 + tid) * NB + b];
    tokB[tid] = r_tok[(hr * 80 + tid) * NB + b];
    attB[tid] = r_att[(hr * 80 + tid) * NB + b];
  }

  float acc[5][5];
#pragma unroll
  for (int i = 0; i < 5; ++i)
#pragma unroll
    for (int j = 0; j < 5; ++j) acc[i][j] = 0.f;

  for (int kc = 0; kc < 352; kc += 32){
    __syncthreads();
    // stage 2 sides x 80 rows x 16 float2 (32 k) = 2560 ops / 256 thr
#pragma unroll
    for (int it = 0; it < 10; ++it){
      int i = tid + it * 256;
      int side = i >= 1280;
      int rem = i - side * 1280;
      int r = rem >> 4, pr = rem & 15;
      int k0 = kc + pr * 2;
      float vx = 0.f, vy = 0.f;
      if (k0 < 50){
        int aid = side ? attB[r] : attA[r];
        const float* s = aemb + aid * 50 + k0;
        vx = s[0]; vy = s[1];
      } else if (k0 < 350){
        int tkn = side ? tokB[r] : tokA[r];
        const float* s = wemb + (size_t)tkn * 300 + (k0 - 50);
        vx = s[0]; vy = s[1];
      }
      float* dst = side ? &Rt[r][pr * 2] : &Lt[r][pr * 2];
      dst[0] = vx; dst[1] = vy;
    }
    __syncthreads();
#pragma unroll 1
    for (int g = 0; g < 8; ++g){
      f32x4 Rb[5];
#pragma unroll
      for (int j = 0; j < 5; ++j) Rb[j] = *(const f32x4*)&Rt[tx + 16 * j][g * 4];
#pragma unroll
      for (int i = 0; i < 5; ++i){
        f32x4 La = *(const f32x4*)&Lt[ty + 16 * i][g * 4];
#pragma unroll
        for (int j = 0; j < 5; ++j){
          acc[i][j] = fmaf(La[0], Rb[j][0], acc[i][j]);
          acc[i][j] = fmaf(La[1], Rb[j][1], acc[i][j]);
          acc[i][j] = fmaf(La[2], Rb[j][2], acc[i][j]);
          acc[i][j] = fmaf(La[3], Rb[j][3], acc[i][j]);
        }
      }
    }
  }

  const int ll = llen[b], rl = rlen[b];
#pragma unroll
  for (int i = 0; i < 5; ++i){
    int row = hl * 80 + ty + 16 * i;
    bool lok = row < ll;
#pragma unroll
    for (int j = 0; j < 5; ++j){
      int col = hr * 80 + tx + 16 * j;
      if (!(lok && (col < rl))) acc[i][j] = 0.f;
      att[((size_t)bl * 160 + row) * 160 + col] = acc[i][j];
    }
  }
  // transposed store via LDS (validated pattern, 80-range)
  for (int jj = 0; jj < 5; ++jj){
    __syncthreads();
#pragma unroll
    for (int i = 0; i < 5; ++i) Tb[tx][ty + 16 * i] = acc[i][jj];
    __syncthreads();
    for (int i2 = tid; i2 < 16 * 80; i2 += 256){
      int rloc = i2 / 80, l = i2 - rloc * 80;
      attT[((size_t)bl * 160 + hr * 80 + 16 * jj + rloc) * 160 + hl * 80 + l]
          = Tb[rloc][l];
    }
  }
}

// ---------------- 2. per-row softmax+renorm, w, top-3, counter, |diff| ------
// attR rows contiguous over kv. Output split-bf16 planes, K-padded to 352.
__global__ __launch_bounds__(256) void proc_kernel(
    const float* __restrict__ attR,
    const int* __restrict__ ownLen, const int* __restrict__ kvLen,
    const int* __restrict__ ownTok, const int* __restrict__ ownAttr,
    const int* __restrict__ kvTok,  const int* __restrict__ kvAttr,
    const float* __restrict__ wemb, const float* __restrict__ aemb,
    unsigned short* __restrict__ outH, unsigned short* __restrict__ outL,
    int CB, int b0){
  int lane = threadIdx.x & 63;
  int wid = blockIdx.x * 4 + (threadIdx.x >> 6);
  int q  = wid / CB;
  int bl = wid - q * CB;
  int b  = b0 + bl;
  int nOwn = ownLen[b], nKv = kvLen[b];
  const float* __restrict__ row = attR + ((size_t)bl * 160 + q) * 160;
  int rr0 = lane, rr1 = lane + 64, rr2 = lane + 128;
  bool has2 = rr2 < 160;
  float a0 = row[rr0];
  float a1 = row[rr1];
  float a2 = has2 ? row[rr2] : 0.f;
  float v0 = (rr0 < nKv) ? a0 : -10.f;
  float v1 = (rr1 < nKv) ? a1 : -10.f;
  float v2 = has2 ? ((rr2 < nKv) ? a2 : -10.f) : -1e30f;
  float m = wmaxf(fmaxf(v0, fmaxf(v1, v2)));
  float e0 = expf(v0 - m);
  float e1 = expf(v1 - m);
  float e2 = has2 ? expf(v2 - m) : 0.f;
  float ssum = wsum(e0 + e1 + e2);
  float p0 = (rr0 < nKv) ? e0 / ssum : 0.f;
  float p1 = (rr1 < nKv) ? e1 / ssum : 0.f;
  float p2 = (has2 && rr2 < nKv) ? e2 / ssum : 0.f;
  float s2 = wsum(p0 + p1 + p2);
  float inv = 1.f / (s2 + 1e-13f);
  p0 *= inv; p1 *= inv; p2 *= inv;
  float sp  = wsum(p0 + p1 + p2);
  float sp2 = wsum(p0 * p0 + p1 * p1 + p2 * p2);
  float kf = (float)nKv;
  float mean = sp / kf;
  float w = (sp2 / kf - mean * mean) / fmaxf(mean, 0.001f);
  // top-3, JAX tie-break (lower index wins ties)
  unsigned long long key0 = (((unsigned long long)__float_as_uint(p0)) << 32) | (unsigned)(0xFFFFFFFFu - rr0);
  unsigned long long key1 = (((unsigned long long)__float_as_uint(p1)) << 32) | (unsigned)(0xFFFFFFFFu - rr1);
  unsigned long long key2 = has2 ? ((((unsigned long long)__float_as_uint(p2)) << 32) | (unsigned)(0xFFFFFFFFu - rr2)) : 0ull;
  float tv[3]; int ti[3];
#pragma unroll
  for (int kk = 0; kk < 3; ++kk){
    unsigned long long loc = key0 > key1 ? key0 : key1;
    loc = key2 > loc ? key2 : loc;
    unsigned long long g = wmax64(loc);
    tv[kk] = __uint_as_float((unsigned)(g >> 32));
    ti[kk] = (int)(0xFFFFFFFFu - (unsigned)g);
    if (key0 == g) key0 = 0ull;
    if (key1 == g) key1 = 0ull;
    if (key2 == g) key2 = 0ull;
  }
  float tsum = tv[0] + tv[1] + tv[2];
  float ad = 1.f / fmaxf(tsum, 0.001f);
  float c0 = tv[0] * ad, c1 = tv[1] * ad, c2 = tv[2] * ad;
  size_t rb = ((size_t)q * CB + bl) * 352;
  unsigned short* __restrict__ oh = outH + rb;
  unsigned short* __restrict__ ol = outL + rb;
  if (q < nOwn){
    int oa = ownAttr[q * NB + b],    ot = ownTok[q * NB + b];
    int a0i = kvAttr[ti[0] * NB + b], t0 = kvTok[ti[0] * NB + b];
    int a1i = kvAttr[ti[1] * NB + b], t1 = kvTok[ti[1] * NB + b];
    int a2i = kvAttr[ti[2] * NB + b], t2 = kvTok[ti[2] * NB + b];
    // attr region d in [0,50): scalar
    if (lane < 50){
      int d = lane;
      float ov = aemb[oa * 50 + d];
      float cc = c0 * aemb[a0i * 50 + d] + c1 * aemb[a1i * 50 + d]
               + c2 * aemb[a2i * 50 + d];
      float val = w * fabsf(ov - cc);
      unsigned short hb = f2bf(val);
      oh[d] = hb; ol[d] = f2bf(val - bf2f(hb));
    }
    // word region: 75 groups of float4 (wemb rows are 1200B = 16B-aligned)
    for (int j = lane; j < 75; j += 64){
      int d = 50 + j * 4;
      f32x4 ov = *(const f32x4*)(wemb + (size_t)ot * 300 + j * 4);
      f32x4 k0 = *(const f32x4*)(wemb + (size_t)t0 * 300 + j * 4);
      f32x4 k1 = *(const f32x4*)(wemb + (size_t)t1 * 300 + j * 4);
      f32x4 k2 = *(const f32x4*)(wemb + (size_t)t2 * 300 + j * 4);
      unsigned short hs[4], ls[4];
#pragma unroll
      for (int t = 0; t < 4; ++t){
        float cc = c0 * k0[t] + c1 * k1[t] + c2 * k2[t];
        float val = w * fabsf(ov[t] - cc);
        hs[t] = f2bf(val);
        ls[t] = f2bf(val - bf2f(hs[t]));
      }
      *(unsigned*)(oh + d)     = (unsigned)hs[0] | ((unsigned)hs[1] << 16);
      *(unsigned*)(oh + d + 2) = (unsigned)hs[2] | ((unsigned)hs[3] << 16);
      *(unsigned*)(ol + d)     = (unsigned)ls[0] | ((unsigned)ls[1] << 16);
      *(unsigned*)(ol + d + 2) = (unsigned)ls[2] | ((unsigned)ls[3] << 16);
    }
    if (lane == 0){
      *(unsigned*)(oh + 350) = 0u;
      *(unsigned*)(ol + 350) = 0u;
    }
  } else {
    for (int i = lane; i < 176; i += 64){
      *(unsigned*)(oh + i * 2) = 0u;
      *(unsigned*)(ol + i * 2) = 0u;
    }
  }
}

// ---------------- 3. pack conv weights into split-bf16 Wcat (640 x 352) ----
__global__ __launch_bounds__(256) void wcat_kernel(
    const float* __restrict__ w1, const float* __restrict__ w2,
    const float* __restrict__ w3,
    unsigned short* __restrict__ wcatH, unsigned short* __restrict__ wcatL){
  int idx = blockIdx.x * 256 + threadIdx.x;
  if (idx >= 640 * 352) return;
  int c = idx / 352, d = idx - c * 352;
  float v = 0.f;
  if (c < 600 && d < 350){
    if (c < 100) v = w1[c * 350 + d];
    else if (c < 300){
      int cc = c - 100; int j = cc / 100; int o = cc - j * 100;
      v = w2[(o * 350 + d) * 2 + j];
    } else {
      int cc = c - 300; int j = cc / 100; int o = cc - j * 100;
      v = w3[(o * 350 + d) * 3 + j];
    }
  }
  unsigned short hb = f2bf(v);
  wcatH[idx] = hb;
  wcatL[idx] = f2bf(v - bf2f(hb));
}

// ---------------- 3b. zero feats (atomicMax target) -------------------------
__global__ __launch_bounds__(256) void zero_feats(float* __restrict__ feats){
  int i = blockIdx.x * 256 + threadIdx.x;
  if (i < NB * 600) feats[i] = 0.f;
}

// ---------------- 4. P = A(Mx352) @ B^T(352x640) via split-bf16 MFMA -------
// Tile 128x128, 4 waves 2x2 (each 64x64 = 16 frags), 3-pass hi/lo split.
__global__ __launch_bounds__(256) void gemm_mfma(
    const unsigned short* __restrict__ Agh, const unsigned short* __restrict__ Agl,
    const unsigned short* __restrict__ Bgh, const unsigned short* __restrict__ Bgl,
    float* __restrict__ P){
  __shared__ unsigned short Ah[128][40];
  __shared__ unsigned short Al[128][40];
  __shared__ unsigned short Bh[128][40];
  __shared__ unsigned short Bl[128][40];
  const int m0 = blockIdx.x * 128;
  const int n0 = blockIdx.y * 128;
  const int tid = threadIdx.x;
  const int lane = tid & 63;
  const int wid  = tid >> 6;
  const int wr = wid >> 1, wc = wid & 1;
  const int lrow = lane & 15, lkg = lane >> 4;

  const int srow = tid >> 2;   // 0..63
  const int sq   = tid & 3;
  const size_t Aoff0 = (size_t)(m0 + srow)      * 352 + sq * 8;
  const size_t Aoff1 = Aoff0 + (size_t)64 * 352;
  const size_t Boff0 = (size_t)(n0 + srow)      * 352 + sq * 8;
  const size_t Boff1 = Boff0 + (size_t)64 * 352;

  f32x4 acc[4][4];
#pragma unroll
  for (int i = 0; i < 4; ++i)
#pragma unroll
    for (int j = 0; j < 4; ++j) acc[i][j] = (f32x4){0.f, 0.f, 0.f, 0.f};

  u16x8 rah0 = *(const u16x8*)(Agh + Aoff0);
  u16x8 rah1 = *(const u16x8*)(Agh + Aoff1);
  u16x8 ral0 = *(const u16x8*)(Agl + Aoff0);
  u16x8 ral1 = *(const u16x8*)(Agl + Aoff1);
  u16x8 rbh0 = *(const u16x8*)(Bgh + Boff0);
  u16x8 rbh1 = *(const u16x8*)(Bgh + Boff1);
  u16x8 rbl0 = *(const u16x8*)(Bgl + Boff0);
  u16x8 rbl1 = *(const u16x8*)(Bgl + Boff1);

  for (int ks = 0; ks < 11; ++ks){
    __syncthreads();
    *(u16x8*)&Ah[srow][sq * 8]      = rah0;
    *(u16x8*)&Ah[srow + 64][sq * 8] = rah1;
    *(u16x8*)&Al[srow][sq * 8]      = ral0;
    *(u16x8*)&Al[srow + 64][sq * 8] = ral1;
    *(u16x8*)&Bh[srow][sq * 8]      = rbh0;
    *(u16x8*)&Bh[srow + 64][sq * 8] = rbh1;
    *(u16x8*)&Bl[srow][sq * 8]      = rbl0;
    *(u16x8*)&Bl[srow + 64][sq * 8] = rbl1;
    if (ks < 10){
      int k1 = (ks + 1) * 32;
      rah0 = *(const u16x8*)(Agh + Aoff0 + k1);
      rah1 = *(const u16x8*)(Agh + Aoff1 + k1);
      ral0 = *(const u16x8*)(Agl + Aoff0 + k1);
      ral1 = *(const u16x8*)(Agl + Aoff1 + k1);
      rbh0 = *(const u16x8*)(Bgh + Boff0 + k1);
      rbh1 = *(const u16x8*)(Bgh + Boff1 + k1);
      rbl0 = *(const u16x8*)(Bgl + Boff0 + k1);
      rbl1 = *(const u16x8*)(Bgl + Boff1 + k1);
    }
    __syncthreads();

    bf16x8 fah[4], fal[4], fbh[4], fbl[4];
#pragma unroll
    for (int mi = 0; mi < 4; ++mi){
      int r = wr * 64 + mi * 16 + lrow;
      fah[mi] = *(const bf16x8*)&Ah[r][lkg * 8];
      fal[mi] = *(const bf16x8*)&Al[r][lkg * 8];
    }
#pragma unroll
    for (int nj = 0; nj < 4; ++nj){
      int r = wc * 64 + nj * 16 + lrow;
      fbh[nj] = *(const bf16x8*)&Bh[r][lkg * 8];
      fbl[nj] = *(const bf16x8*)&Bl[r][lkg * 8];
    }
#pragma unroll
    for (int mi = 0; mi < 4; ++mi)
#pragma unroll
      for (int nj = 0; nj < 4; ++nj){
        acc[mi][nj] = __builtin_amdgcn_mfma_f32_16x16x32_bf16(fah[mi], fbh[nj], acc[mi][nj], 0, 0, 0);
        acc[mi][nj] = __builtin_amdgcn_mfma_f32_16x16x32_bf16(fal[mi], fbh[nj], acc[mi][nj], 0, 0, 0);
        acc[mi][nj] = __builtin_amdgcn_mfma_f32_16x16x32_bf16(fah[mi], fbl[nj], acc[mi][nj], 0, 0, 0);
      }
  }

#pragma unroll
  for (int mi = 0; mi < 4; ++mi){
#pragma unroll
    for (int nj = 0; nj < 4; ++nj){
      int col = n0 + wc * 64 + nj * 16 + lrow;
      if (col < 600){
        size_t rowb = (size_t)(m0 + wr * 64 + mi * 16 + lkg * 4) * 600 + col;
#pragma unroll
        for (int r = 0; r < 4; ++r)
          P[rowb + (size_t)r * 600] = acc[mi][nj][r];
      }
    }
  }
}

// ---------------- 5. combine: parallel over t-chunks, atomicMax into feats --
__global__ __launch_bounds__(320) void combine_kernel(
    const float* __restrict__ P, const int* __restrict__ len,
    const float* __restrict__ b1, const float* __restrict__ b2,
    const float* __restrict__ b3, float* __restrict__ feats,
    int sideoff, int CB, int b0){
  int bl = blockIdx.x;
  int tc = blockIdx.y;
  int b = b0 + bl;
  int c = threadIdx.x;
  if (c >= 300) return;
  int n = len[b];
  int t0 = tc * 32;
  float vmax = 0.f;   // relu floor
  if (c < 100){
    int te = min(t0 + 32, n);
    float bias = b1[c];
    for (int t = t0; t < te; ++t)
      vmax = fmaxf(vmax, P[(size_t)(t * CB + bl) * 600 + c] + bias);
  } else if (c < 200){
    int o = c - 100;
    int te = min(t0 + 32, n - 1);
    float bias = b2[o];
    for (int t = t0; t < te; ++t)
      vmax = fmaxf(vmax, P[(size_t)(t * CB + bl) * 600 + 100 + o]
                       + P[(size_t)((t + 1) * CB + bl) * 600 + 200 + o] + bias);
  } else {
    int o = c - 200;
    int te = min(t0 + 32, n - 2);
    float bias = b3[o];
    for (int t = t0; t < te; ++t)
      vmax = fmaxf(vmax, P[(size_t)(t * CB + bl) * 600 + 300 + o]
                       + P[(size_t)((t + 1) * CB + bl) * 600 + 400 + o]
                       + P[(size_t)((t + 2) * CB + bl) * 600 + 500 + o] + bias);
  }
  atomicMax((int*)&feats[(size_t)b * 600 + sideoff + c], __float_as_int(vmax));
}

// ---------------- 6. dense head ---------------------------------------------
__global__ __launch_bounds__(64) void dense_kernel(
    const float* __restrict__ feats,
    const float* __restrict__ w1, const float* __restrict__ b1,
    const float* __restrict__ w2, const float* __restrict__ b2,
    float* __restrict__ out){
  __shared__ float fs[600];
  __shared__ float hs[60];
  int b = blockIdx.x, tid = threadIdx.x;
  for (int i = tid; i < 600; i += 64) fs[i] = feats[(size_t)b * 600 + i];
  __syncthreads();
  if (tid < 60){
    float s = b1[tid];
    for (int d = 0; d < 600; ++d) s = fmaf(fs[d], w1[d * 60 + tid], s);
    hs[tid] = fmaxf(s, 0.f);
  }
  __syncthreads();
  if (tid < 2){
    float s = b2[tid];
    for (int j = 0; j < 60; ++j) s = fmaf(hs[j], w2[j * 2 + tid], s);
    out[b * 2 + tid] = s;
  }
}

// ---------------- launch ----------------------------------------------------
extern "C" void kernel_launch(void* const* d_in, const int* in_sizes, int n_in,
                              void* d_out, int out_size, void* d_ws, size_t ws_size,
                              hipStream_t stream){
  const int*   l_tok = (const int*)d_in[0];
  const int*   l_att = (const int*)d_in[1];
  const int*   l_len = (const int*)d_in[2];
  const int*   r_tok = (const int*)d_in[3];
  const int*   r_att = (const int*)d_in[4];
  const int*   r_len = (const int*)d_in[5];
  const float* wemb  = (const float*)d_in[6];
  const float* aemb  = (const float*)d_in[7];
  const float* cw1   = (const float*)d_in[8];
  const float* cb1   = (const float*)d_in[9];
  const float* cw2   = (const float*)d_in[10];
  const float* cb2   = (const float*)d_in[11];
  const float* cw3   = (const float*)d_in[12];
  const float* cb3   = (const float*)d_in[13];
  const float* dw1   = (const float*)d_in[14];
  const float* db1   = (const float*)d_in[15];
  const float* dw2   = (const float*)d_in[16];
  const float* db2   = (const float*)d_in[17];
  float* out = (float*)d_out;

  // per-batch bytes: att+attT 204800, lc/rc planes 450560, P 384000
  //   => 1,039,360.  persistent: feats 1,228,800 + wcat 901,120.
  // CB power of two (>=4) so 128 | 160*CB.
  int CB = 512;
  while (CB > 4){
    size_t need = (size_t)CB * 1039360 + 2129920 + 4096;
    if (need <= ws_size) break;
    CB >>= 1;
  }

  char* p = (char*)d_ws;
  float* feats = (float*)p;                   p += 1228800;
  unsigned short* wcatH = (unsigned short*)p; p += 450560;
  unsigned short* wcatL = (unsigned short*)p; p += 450560;
  float* att  = (float*)p;                    p += (size_t)CB * 102400;
  float* attT = (float*)p;                    p += (size_t)CB * 102400;
  unsigned short* lcH = (unsigned short*)p;   p += (size_t)CB * 112640;
  unsigned short* lcL = (unsigned short*)p;   p += (size_t)CB * 112640;
  unsigned short* rcH = (unsigned short*)p;   p += (size_t)CB * 112640;
  unsigned short* rcL = (unsigned short*)p;   p += (size_t)CB * 112640;
  float* P = (float*)p;

  wcat_kernel<<<880, 256, 0, stream>>>(cw1, cw2, cw3, wcatH, wcatL);
  zero_feats<<<1200, 256, 0, stream>>>(feats);

  int nch = NB / CB;
  dim3 gA(CB, 4);
  dim3 gP(CB * 160 / 128, 5);
  dim3 gC(CB, 5);
  for (int c = 0; c < nch; ++c){
    int b0 = c * CB;
    att_tile<<<gA, 256, 0, stream>>>(l_tok, l_att, r_tok, r_att, wemb, aemb,
                                     l_len, r_len, att, attT, b0);
    proc_kernel<<<CB * 40, 256, 0, stream>>>(att,  l_len, r_len,
                                             l_tok, l_att, r_tok, r_att,
                                             wemb, aemb, lcH, lcL, CB, b0);
    proc_kernel<<<CB * 40, 256, 0, stream>>>(attT, r_len, l_len,
                                             r_tok, r_att, l_tok, l_att,
                                             wemb, aemb, rcH, rcL, CB, b0);
    gemm_mfma<<<gP, 256, 0, stream>>>(lcH, lcL, wcatH, wcatL, P);
    combine_kernel<<<gC, 320, 0, stream>>>(P, l_len, cb1, cb2, cb3, feats, 0,   CB, b0);
    gemm_mfma<<<gP, 256, 0, stream>>>(rcH, rcL, wcatH, wcatL, P);
    combine_kernel<<<gC, 320, 0, stream>>>(P, r_len, cb1, cb2, cb3, feats, 300, CB, b0);
  }
  dense_kernel<<<NB, 64, 0, stream>>>(feats, dw1, db1, dw2, db2, out);
}

// Round 12
// 874.792 us; speedup vs baseline: 1.8036x; 1.0491x over previous
//
#include <hip/hip_runtime.h>
#include <hip/hip_bf16.h>

#define NB 512
#define NL 160
#define ND 350

typedef float f32x4 __attribute__((ext_vector_type(4)));
typedef __bf16 bf16x8 __attribute__((ext_vector_type(8)));
typedef unsigned short u16x8 __attribute__((ext_vector_type(8)));

// ---------------- wave (64-lane) reductions ----------------
__device__ __forceinline__ float wsum(float v){
#pragma unroll
  for (int o = 32; o; o >>= 1) v += __shfl_xor(v, o, 64);
  return v;
}
__device__ __forceinline__ float wmaxf(float v){
#pragma unroll
  for (int o = 32; o; o >>= 1) v = fmaxf(v, __shfl_xor(v, o, 64));
  return v;
}
__device__ __forceinline__ unsigned long long wmax64(unsigned long long v){
#pragma unroll
  for (int o = 32; o; o >>= 1){
    unsigned long long u = __shfl_xor(v, o, 64);
    v = (u > v) ? u : v;
  }
  return v;
}

// float -> bf16 bits (RNE), and back
__device__ __forceinline__ unsigned short f2bf(float f){
  unsigned x = __float_as_uint(f);
  unsigned r = (x + 0x7fffu + ((x >> 16) & 1u)) >> 16;
  return (unsigned short)r;
}
__device__ __forceinline__ float bf2f(unsigned short u){
  return __uint_as_float(((unsigned)u) << 16);
}

// ---------------- 1. att quadrants: 80x80 per block, grid (CB, 4) -----------
// Early-exit: a quadrant with hl*80 >= ll or hr*80 >= rl writes NOTHING —
// masked att/attT values are never consumed downstream (proc substitutes -10
// past kv-len and zero-writes past own-len without reading att).
__global__ __launch_bounds__(256, 2) void att_tile(
    const int* __restrict__ l_tok, const int* __restrict__ l_att,
    const int* __restrict__ r_tok, const int* __restrict__ r_att,
    const float* __restrict__ wemb, const float* __restrict__ aemb,
    const int* __restrict__ llen, const int* __restrict__ rlen,
    float* __restrict__ att, float* __restrict__ attT, int b0){
  __shared__ __align__(16) char smem[2 * 80 * 36 * 4];    // 23,040 B
  float (*Lt)[36] = (float (*)[36])smem;
  float (*Rt)[36] = (float (*)[36])(smem + 80 * 36 * 4);
  float (*Tb)[84] = (float (*)[84])smem;                  // epilogue alias
  __shared__ int tokA[80], attA[80], tokB[80], attB[80];

  const int bl = blockIdx.x;
  const int b  = b0 + bl;
  const int hl = blockIdx.y >> 1, hr = blockIdx.y & 1;
  const int ll = llen[b], rl = rlen[b];
  if (hl * 80 >= ll || hr * 80 >= rl) return;   // dead quadrant: values unused

  const int tid = threadIdx.x;
  const int tx = tid & 15, ty = tid >> 4;

  if (tid < 80){
    tokA[tid] = l_tok[(hl * 80 + tid) * NB + b];
    attA[tid] = l_att[(hl * 80 + tid) * NB + b];
    tokB[tid] = r_tok[(hr * 80 + tid) * NB + b];
    attB[tid] = r_att[(hr * 80 + tid) * NB + b];
  }

  float acc[5][5];
#pragma unroll
  for (int i = 0; i < 5; ++i)
#pragma unroll
    for (int j = 0; j < 5; ++j) acc[i][j] = 0.f;

  for (int kc = 0; kc < 352; kc += 32){
    __syncthreads();
    // stage 2 sides x 80 rows x 16 float2 (32 k) = 2560 ops / 256 thr
#pragma unroll
    for (int it = 0; it < 10; ++it){
      int i = tid + it * 256;
      int side = i >= 1280;
      int rem = i - side * 1280;
      int r = rem >> 4, pr = rem & 15;
      int k0 = kc + pr * 2;
      float vx = 0.f, vy = 0.f;
      if (k0 < 50){
        int aid = side ? attB[r] : attA[r];
        const float* s = aemb + aid * 50 + k0;
        vx = s[0]; vy = s[1];
      } else if (k0 < 350){
        int tkn = side ? tokB[r] : tokA[r];
        const float* s = wemb + (size_t)tkn * 300 + (k0 - 50);
        vx = s[0]; vy = s[1];
      }
      float* dst = side ? &Rt[r][pr * 2] : &Lt[r][pr * 2];
      dst[0] = vx; dst[1] = vy;
    }
    __syncthreads();
#pragma unroll 1
    for (int g = 0; g < 8; ++g){
      f32x4 Rb[5];
#pragma unroll
      for (int j = 0; j < 5; ++j) Rb[j] = *(const f32x4*)&Rt[tx + 16 * j][g * 4];
#pragma unroll
      for (int i = 0; i < 5; ++i){
        f32x4 La = *(const f32x4*)&Lt[ty + 16 * i][g * 4];
#pragma unroll
        for (int j = 0; j < 5; ++j){
          acc[i][j] = fmaf(La[0], Rb[j][0], acc[i][j]);
          acc[i][j] = fmaf(La[1], Rb[j][1], acc[i][j]);
          acc[i][j] = fmaf(La[2], Rb[j][2], acc[i][j]);
          acc[i][j] = fmaf(La[3], Rb[j][3], acc[i][j]);
        }
      }
    }
  }

#pragma unroll
  for (int i = 0; i < 5; ++i){
    int row = hl * 80 + ty + 16 * i;
    bool lok = row < ll;
#pragma unroll
    for (int j = 0; j < 5; ++j){
      int col = hr * 80 + tx + 16 * j;
      if (!(lok && (col < rl))) acc[i][j] = 0.f;
      att[((size_t)bl * 160 + row) * 160 + col] = acc[i][j];
    }
  }
  // transposed store via LDS (validated pattern, 80-range)
  for (int jj = 0; jj < 5; ++jj){
    __syncthreads();
#pragma unroll
    for (int i = 0; i < 5; ++i) Tb[tx][ty + 16 * i] = acc[i][jj];
    __syncthreads();
    for (int i2 = tid; i2 < 16 * 80; i2 += 256){
      int rloc = i2 / 80, l = i2 - rloc * 80;
      attT[((size_t)bl * 160 + hr * 80 + 16 * jj + rloc) * 160 + hl * 80 + l]
          = Tb[rloc][l];
    }
  }
}

// ---------------- 2. per-row softmax+renorm, w, top-3, counter, |diff| ------
// attR rows contiguous over kv. Output split-bf16 planes, K-padded to 352.
// Waves with q >= nOwn (wave-uniform) write zeros and return early — no att
// read, no softmax/top-k.
__global__ __launch_bounds__(256) void proc_kernel(
    const float* __restrict__ attR,
    const int* __restrict__ ownLen, const int* __restrict__ kvLen,
    const int* __restrict__ ownTok, const int* __restrict__ ownAttr,
    const int* __restrict__ kvTok,  const int* __restrict__ kvAttr,
    const float* __restrict__ wemb, const float* __restrict__ aemb,
    unsigned short* __restrict__ outH, unsigned short* __restrict__ outL,
    int CB, int b0){
  int lane = threadIdx.x & 63;
  int wid = blockIdx.x * 4 + (threadIdx.x >> 6);
  int q  = wid / CB;
  int bl = wid - q * CB;
  int b  = b0 + bl;
  int nOwn = ownLen[b], nKv = kvLen[b];
  size_t rb = ((size_t)q * CB + bl) * 352;
  unsigned short* __restrict__ oh = outH + rb;
  unsigned short* __restrict__ ol = outL + rb;
  if (q >= nOwn){          // wave-uniform: zero rows for the GEMM, skip rest
    for (int i = lane; i < 176; i += 64){
      *(unsigned*)(oh + i * 2) = 0u;
      *(unsigned*)(ol + i * 2) = 0u;
    }
    return;
  }
  const float* __restrict__ row = attR + ((size_t)bl * 160 + q) * 160;
  int rr0 = lane, rr1 = lane + 64, rr2 = lane + 128;
  bool has2 = rr2 < 160;
  float a0 = row[rr0];
  float a1 = row[rr1];
  float a2 = has2 ? row[rr2] : 0.f;
  float v0 = (rr0 < nKv) ? a0 : -10.f;
  float v1 = (rr1 < nKv) ? a1 : -10.f;
  float v2 = has2 ? ((rr2 < nKv) ? a2 : -10.f) : -1e30f;
  float m = wmaxf(fmaxf(v0, fmaxf(v1, v2)));
  float e0 = expf(v0 - m);
  float e1 = expf(v1 - m);
  float e2 = has2 ? expf(v2 - m) : 0.f;
  float ssum = wsum(e0 + e1 + e2);
  float p0 = (rr0 < nKv) ? e0 / ssum : 0.f;
  float p1 = (rr1 < nKv) ? e1 / ssum : 0.f;
  float p2 = (has2 && rr2 < nKv) ? e2 / ssum : 0.f;
  float s2 = wsum(p0 + p1 + p2);
  float inv = 1.f / (s2 + 1e-13f);
  p0 *= inv; p1 *= inv; p2 *= inv;
  float sp  = wsum(p0 + p1 + p2);
  float sp2 = wsum(p0 * p0 + p1 * p1 + p2 * p2);
  float kf = (float)nKv;
  float mean = sp / kf;
  float w = (sp2 / kf - mean * mean) / fmaxf(mean, 0.001f);
  // top-3, JAX tie-break (lower index wins ties)
  unsigned long long key0 = (((unsigned long long)__float_as_uint(p0)) << 32) | (unsigned)(0xFFFFFFFFu - rr0);
  unsigned long long key1 = (((unsigned long long)__float_as_uint(p1)) << 32) | (unsigned)(0xFFFFFFFFu - rr1);
  unsigned long long key2 = has2 ? ((((unsigned long long)__float_as_uint(p2)) << 32) | (unsigned)(0xFFFFFFFFu - rr2)) : 0ull;
  float tv[3]; int ti[3];
#pragma unroll
  for (int kk = 0; kk < 3; ++kk){
    unsigned long long loc = key0 > key1 ? key0 : key1;
    loc = key2 > loc ? key2 : loc;
    unsigned long long g = wmax64(loc);
    tv[kk] = __uint_as_float((unsigned)(g >> 32));
    ti[kk] = (int)(0xFFFFFFFFu - (unsigned)g);
    if (key0 == g) key0 = 0ull;
    if (key1 == g) key1 = 0ull;
    if (key2 == g) key2 = 0ull;
  }
  float tsum = tv[0] + tv[1] + tv[2];
  float ad = 1.f / fmaxf(tsum, 0.001f);
  float c0 = tv[0] * ad, c1 = tv[1] * ad, c2 = tv[2] * ad;
  int oa = ownAttr[q * NB + b],    ot = ownTok[q * NB + b];
  int a0i = kvAttr[ti[0] * NB + b], t0 = kvTok[ti[0] * NB + b];
  int a1i = kvAttr[ti[1] * NB + b], t1 = kvTok[ti[1] * NB + b];
  int a2i = kvAttr[ti[2] * NB + b], t2 = kvTok[ti[2] * NB + b];
  // attr region d in [0,50): scalar
  if (lane < 50){
    int d = lane;
    float ov = aemb[oa * 50 + d];
    float cc = c0 * aemb[a0i * 50 + d] + c1 * aemb[a1i * 50 + d]
             + c2 * aemb[a2i * 50 + d];
    float val = w * fabsf(ov - cc);
    unsigned short hb = f2bf(val);
    oh[d] = hb; ol[d] = f2bf(val - bf2f(hb));
  }
  // word region: 75 groups of float4 (wemb rows are 1200B = 16B-aligned)
  for (int j = lane; j < 75; j += 64){
    int d = 50 + j * 4;
    f32x4 ov = *(const f32x4*)(wemb + (size_t)ot * 300 + j * 4);
    f32x4 k0 = *(const f32x4*)(wemb + (size_t)t0 * 300 + j * 4);
    f32x4 k1 = *(const f32x4*)(wemb + (size_t)t1 * 300 + j * 4);
    f32x4 k2 = *(const f32x4*)(wemb + (size_t)t2 * 300 + j * 4);
    unsigned short hs[4], ls[4];
#pragma unroll
    for (int t = 0; t < 4; ++t){
      float cc = c0 * k0[t] + c1 * k1[t] + c2 * k2[t];
      float val = w * fabsf(ov[t] - cc);
      hs[t] = f2bf(val);
      ls[t] = f2bf(val - bf2f(hs[t]));
    }
    *(unsigned*)(oh + d)     = (unsigned)hs[0] | ((unsigned)hs[1] << 16);
    *(unsigned*)(oh + d + 2) = (unsigned)hs[2] | ((unsigned)hs[3] << 16);
    *(unsigned*)(ol + d)     = (unsigned)ls[0] | ((unsigned)ls[1] << 16);
    *(unsigned*)(ol + d + 2) = (unsigned)ls[2] | ((unsigned)ls[3] << 16);
  }
  if (lane == 0){
    *(unsigned*)(oh + 350) = 0u;
    *(unsigned*)(ol + 350) = 0u;
  }
}

// ---------------- 3. pack conv weights into split-bf16 Wcat (640 x 352) ----
__global__ __launch_bounds__(256) void wcat_kernel(
    const float* __restrict__ w1, const float* __restrict__ w2,
    const float* __restrict__ w3,
    unsigned short* __restrict__ wcatH, unsigned short* __restrict__ wcatL){
  int idx = blockIdx.x * 256 + threadIdx.x;
  if (idx >= 640 * 352) return;
  int c = idx / 352, d = idx - c * 352;
  float v = 0.f;
  if (c < 600 && d < 350){
    if (c < 100) v = w1[c * 350 + d];
    else if (c < 300){
      int cc = c - 100; int j = cc / 100; int o = cc - j * 100;
      v = w2[(o * 350 + d) * 2 + j];
    } else {
      int cc = c - 300; int j = cc / 100; int o = cc - j * 100;
      v = w3[(o * 350 + d) * 3 + j];
    }
  }
  unsigned short hb = f2bf(v);
  wcatH[idx] = hb;
  wcatL[idx] = f2bf(v - bf2f(hb));
}

// ---------------- 3b. zero feats (atomicMax target) -------------------------
__global__ __launch_bounds__(256) void zero_feats(float* __restrict__ feats){
  int i = blockIdx.x * 256 + threadIdx.x;
  if (i < NB * 600) feats[i] = 0.f;
}

// ---------------- 4. P = A(Mx352) @ B^T(352x640) via split-bf16 MFMA -------
// Tile 128x128, 4 waves 2x2 (each 64x64 = 16 frags), 3-pass hi/lo split.
__global__ __launch_bounds__(256) void gemm_mfma(
    const unsigned short* __restrict__ Agh, const unsigned short* __restrict__ Agl,
    const unsigned short* __restrict__ Bgh, const unsigned short* __restrict__ Bgl,
    float* __restrict__ P){
  __shared__ unsigned short Ah[128][40];
  __shared__ unsigned short Al[128][40];
  __shared__ unsigned short Bh[128][40];
  __shared__ unsigned short Bl[128][40];
  const int m0 = blockIdx.x * 128;
  const int n0 = blockIdx.y * 128;
  const int tid = threadIdx.x;
  const int lane = tid & 63;
  const int wid  = tid >> 6;
  const int wr = wid >> 1, wc = wid & 1;
  const int lrow = lane & 15, lkg = lane >> 4;

  const int srow = tid >> 2;   // 0..63
  const int sq   = tid & 3;
  const size_t Aoff0 = (size_t)(m0 + srow)      * 352 + sq * 8;
  const size_t Aoff1 = Aoff0 + (size_t)64 * 352;
  const size_t Boff0 = (size_t)(n0 + srow)      * 352 + sq * 8;
  const size_t Boff1 = Boff0 + (size_t)64 * 352;

  f32x4 acc[4][4];
#pragma unroll
  for (int i = 0; i < 4; ++i)
#pragma unroll
    for (int j = 0; j < 4; ++j) acc[i][j] = (f32x4){0.f, 0.f, 0.f, 0.f};

  u16x8 rah0 = *(const u16x8*)(Agh + Aoff0);
  u16x8 rah1 = *(const u16x8*)(Agh + Aoff1);
  u16x8 ral0 = *(const u16x8*)(Agl + Aoff0);
  u16x8 ral1 = *(const u16x8*)(Agl + Aoff1);
  u16x8 rbh0 = *(const u16x8*)(Bgh + Boff0);
  u16x8 rbh1 = *(const u16x8*)(Bgh + Boff1);
  u16x8 rbl0 = *(const u16x8*)(Bgl + Boff0);
  u16x8 rbl1 = *(const u16x8*)(Bgl + Boff1);

  for (int ks = 0; ks < 11; ++ks){
    __syncthreads();
    *(u16x8*)&Ah[srow][sq * 8]      = rah0;
    *(u16x8*)&Ah[srow + 64][sq * 8] = rah1;
    *(u16x8*)&Al[srow][sq * 8]      = ral0;
    *(u16x8*)&Al[srow + 64][sq * 8] = ral1;
    *(u16x8*)&Bh[srow][sq * 8]      = rbh0;
    *(u16x8*)&Bh[srow + 64][sq * 8] = rbh1;
    *(u16x8*)&Bl[srow][sq * 8]      = rbl0;
    *(u16x8*)&Bl[srow + 64][sq * 8] = rbl1;
    if (ks < 10){
      int k1 = (ks + 1) * 32;
      rah0 = *(const u16x8*)(Agh + Aoff0 + k1);
      rah1 = *(const u16x8*)(Agh + Aoff1 + k1);
      ral0 = *(const u16x8*)(Agl + Aoff0 + k1);
      ral1 = *(const u16x8*)(Agl + Aoff1 + k1);
      rbh0 = *(const u16x8*)(Bgh + Boff0 + k1);
      rbh1 = *(const u16x8*)(Bgh + Boff1 + k1);
      rbl0 = *(const u16x8*)(Bgl + Boff0 + k1);
      rbl1 = *(const u16x8*)(Bgl + Boff1 + k1);
    }
    __syncthreads();

    bf16x8 fah[4], fal[4], fbh[4], fbl[4];
#pragma unroll
    for (int mi = 0; mi < 4; ++mi){
      int r = wr * 64 + mi * 16 + lrow;
      fah[mi] = *(const bf16x8*)&Ah[r][lkg * 8];
      fal[mi] = *(const bf16x8*)&Al[r][lkg * 8];
    }
#pragma unroll
    for (int nj = 0; nj < 4; ++nj){
      int r = wc * 64 + nj * 16 + lrow;
      fbh[nj] = *(const bf16x8*)&Bh[r][lkg * 8];
      fbl[nj] = *(const bf16x8*)&Bl[r][lkg * 8];
    }
#pragma unroll
    for (int mi = 0; mi < 4; ++mi)
#pragma unroll
      for (int nj = 0; nj < 4; ++nj){
        acc[mi][nj] = __builtin_amdgcn_mfma_f32_16x16x32_bf16(fah[mi], fbh[nj], acc[mi][nj], 0, 0, 0);
        acc[mi][nj] = __builtin_amdgcn_mfma_f32_16x16x32_bf16(fal[mi], fbh[nj], acc[mi][nj], 0, 0, 0);
        acc[mi][nj] = __builtin_amdgcn_mfma_f32_16x16x32_bf16(fah[mi], fbl[nj], acc[mi][nj], 0, 0, 0);
      }
  }

#pragma unroll
  for (int mi = 0; mi < 4; ++mi){
#pragma unroll
    for (int nj = 0; nj < 4; ++nj){
      int col = n0 + wc * 64 + nj * 16 + lrow;
      if (col < 600){
        size_t rowb = (size_t)(m0 + wr * 64 + mi * 16 + lkg * 4) * 600 + col;
#pragma unroll
        for (int r = 0; r < 4; ++r)
          P[rowb + (size_t)r * 600] = acc[mi][nj][r];
      }
    }
  }
}

// ---------------- 5. combine: parallel over t-chunks, atomicMax into feats --
__global__ __launch_bounds__(320) void combine_kernel(
    const float* __restrict__ P, const int* __restrict__ len,
    const float* __restrict__ b1, const float* __restrict__ b2,
    const float* __restrict__ b3, float* __restrict__ feats,
    int sideoff, int CB, int b0){
  int bl = blockIdx.x;
  int tc = blockIdx.y;
  int b = b0 + bl;
  int c = threadIdx.x;
  if (c >= 300) return;
  int n = len[b];
  int t0 = tc * 32;
  float vmax = 0.f;   // relu floor
  if (c < 100){
    int te = min(t0 + 32, n);
    float bias = b1[c];
    for (int t = t0; t < te; ++t)
      vmax = fmaxf(vmax, P[(size_t)(t * CB + bl) * 600 + c] + bias);
  } else if (c < 200){
    int o = c - 100;
    int te = min(t0 + 32, n - 1);
    float bias = b2[o];
    for (int t = t0; t < te; ++t)
      vmax = fmaxf(vmax, P[(size_t)(t * CB + bl) * 600 + 100 + o]
                       + P[(size_t)((t + 1) * CB + bl) * 600 + 200 + o] + bias);
  } else {
    int o = c - 200;
    int te = min(t0 + 32, n - 2);
    float bias = b3[o];
    for (int t = t0; t < te; ++t)
      vmax = fmaxf(vmax, P[(size_t)(t * CB + bl) * 600 + 300 + o]
                       + P[(size_t)((t + 1) * CB + bl) * 600 + 400 + o]
                       + P[(size_t)((t + 2) * CB + bl) * 600 + 500 + o] + bias);
  }
  atomicMax((int*)&feats[(size_t)b * 600 + sideoff + c], __float_as_int(vmax));
}

// ---------------- 6. dense head ---------------------------------------------
__global__ __launch_bounds__(64) void dense_kernel(
    const float* __restrict__ feats,
    const float* __restrict__ w1, const float* __restrict__ b1,
    const float* __restrict__ w2, const float* __restrict__ b2,
    float* __restrict__ out){
  __shared__ float fs[600];
  __shared__ float hs[60];
  int b = blockIdx.x, tid = threadIdx.x;
  for (int i = tid; i < 600; i += 64) fs[i] = feats[(size_t)b * 600 + i];
  __syncthreads();
  if (tid < 60){
    float s = b1[tid];
    for (int d = 0; d < 600; ++d) s = fmaf(fs[d], w1[d * 60 + tid], s);
    hs[tid] = fmaxf(s, 0.f);
  }
  __syncthreads();
  if (tid < 2){
    float s = b2[tid];
    for (int j = 0; j < 60; ++j) s = fmaf(hs[j], w2[j * 2 + tid], s);
    out[b * 2 + tid] = s;
  }
}

// ---------------- launch ----------------------------------------------------
extern "C" void kernel_launch(void* const* d_in, const int* in_sizes, int n_in,
                              void* d_out, int out_size, void* d_ws, size_t ws_size,
                              hipStream_t stream){
  const int*   l_tok = (const int*)d_in[0];
  const int*   l_att = (const int*)d_in[1];
  const int*   l_len = (const int*)d_in[2];
  const int*   r_tok = (const int*)d_in[3];
  const int*   r_att = (const int*)d_in[4];
  const int*   r_len = (const int*)d_in[5];
  const float* wemb  = (const float*)d_in[6];
  const float* aemb  = (const float*)d_in[7];
  const float* cw1   = (const float*)d_in[8];
  const float* cb1   = (const float*)d_in[9];
  const float* cw2   = (const float*)d_in[10];
  const float* cb2   = (const float*)d_in[11];
  const float* cw3   = (const float*)d_in[12];
  const float* cb3   = (const float*)d_in[13];
  const float* dw1   = (const float*)d_in[14];
  const float* db1   = (const float*)d_in[15];
  const float* dw2   = (const float*)d_in[16];
  const float* db2   = (const float*)d_in[17];
  float* out = (float*)d_out;

  // per-batch bytes: att+attT 204800, lc/rc planes 450560, P 384000
  //   => 1,039,360.  persistent: feats 1,228,800 + wcat 901,120.
  // CB power of two (>=4) so 128 | 160*CB.
  int CB = 512;
  while (CB > 4){
    size_t need = (size_t)CB * 1039360 + 2129920 + 4096;
    if (need <= ws_size) break;
    CB >>= 1;
  }

  char* p = (char*)d_ws;
  float* feats = (float*)p;                   p += 1228800;
  unsigned short* wcatH = (unsigned short*)p; p += 450560;
  unsigned short* wcatL = (unsigned short*)p; p += 450560;
  float* att  = (float*)p;                    p += (size_t)CB * 102400;
  float* attT = (float*)p;                    p += (size_t)CB * 102400;
  unsigned short* lcH = (unsigned short*)p;   p += (size_t)CB * 112640;
  unsigned short* lcL = (unsigned short*)p;   p += (size_t)CB * 112640;
  unsigned short* rcH = (unsigned short*)p;   p += (size_t)CB * 112640;
  unsigned short* rcL = (unsigned short*)p;   p += (size_t)CB * 112640;
  float* P = (float*)p;

  wcat_kernel<<<880, 256, 0, stream>>>(cw1, cw2, cw3, wcatH, wcatL);
  zero_feats<<<1200, 256, 0, stream>>>(feats);

  int nch = NB / CB;
  dim3 gA(CB, 4);
  dim3 gP(CB * 160 / 128, 5);
  dim3 gC(CB, 5);
  for (int c = 0; c < nch; ++c){
    int b0 = c * CB;
    att_tile<<<gA, 256, 0, stream>>>(l_tok, l_att, r_tok, r_att, wemb, aemb,
                                     l_len, r_len, att, attT, b0);
    proc_kernel<<<CB * 40, 256, 0, stream>>>(att,  l_len, r_len,
                                             l_tok, l_att, r_tok, r_att,
                                             wemb, aemb, lcH, lcL, CB, b0);
    proc_kernel<<<CB * 40, 256, 0, stream>>>(attT, r_len, l_len,
                                             r_tok, r_att, l_tok, l_att,
                                             wemb, aemb, rcH, rcL, CB, b0);
    gemm_mfma<<<gP, 256, 0, stream>>>(lcH, lcL, wcatH, wcatL, P);
    combine_kernel<<<gC, 320, 0, stream>>>(P, l_len, cb1, cb2, cb3, feats, 0,   CB, b0);
    gemm_mfma<<<gP, 256, 0, stream>>>(rcH, rcL, wcatH, wcatL, P);
    combine_kernel<<<gC, 320, 0, stream>>>(P, r_len, cb1, cb2, cb3, feats, 300, CB, b0);
  }
  dense_kernel<<<NB, 64, 0, stream>>>(feats, dw1, db1, dw2, db2, out);
}